// Round 1
// baseline (452.143 us; speedup 1.0000x reference)
//
#include <hip/hip_runtime.h>
#include <math.h>

// Problem constants (match reference)
constexpr int T_ = 128, B_ = 32, IN_ = 512, H_ = 8, D_ = 64, ETA_ = 4, R_ = 4;
constexpr int DE_ = ETA_ * D_;          // 256
constexpr float EPS_ = 1e-5f;

__device__ __forceinline__ float sigmoidf_(float x) { return 1.0f / (1.0f + expf(-x)); }

// ---------------------------------------------------------------------------
// Tiled fp32 GEMM: C(MxN) = A(MxK) @ W(NxK)^T + bias(N)
// 64x64 tile, 256 threads, 4x4 micro-tile per thread. M%64==0, K%16==0; N guarded.
// ---------------------------------------------------------------------------
template <int BM, int BN, int BK>
__global__ __launch_bounds__(256) void sgemm_nt(
    const float* __restrict__ A, const float* __restrict__ W,
    const float* __restrict__ bias, float* __restrict__ C,
    int M, int N, int K)
{
    __shared__ __align__(16) float As[BK][BM + 4];
    __shared__ __align__(16) float Bs[BK][BN + 4];

    const int bm = blockIdx.y * BM;
    const int bn = blockIdx.x * BN;
    const int tid = threadIdx.x;
    const int tm = (tid >> 4) << 2;       // 0..60 step 4
    const int tn = (tid & 15) << 2;       // 0..60 step 4
    const int lr = tid >> 2;              // 0..63 (row in tile)
    const int lc = (tid & 3) << 2;        // 0,4,8,12 (k offset)

    float acc[4][4] = {};

    const float* Aptr = A + (size_t)(bm + lr) * K + lc;
    const int wrow = bn + lr;
    const float* Wptr = W + (size_t)wrow * K + lc;
    const bool wok = (wrow < N);

    for (int k0 = 0; k0 < K; k0 += BK) {
        float4 a = *(const float4*)(Aptr + k0);
        float4 w = make_float4(0.f, 0.f, 0.f, 0.f);
        if (wok) w = *(const float4*)(Wptr + k0);
        As[lc + 0][lr] = a.x; As[lc + 1][lr] = a.y; As[lc + 2][lr] = a.z; As[lc + 3][lr] = a.w;
        Bs[lc + 0][lr] = w.x; Bs[lc + 1][lr] = w.y; Bs[lc + 2][lr] = w.z; Bs[lc + 3][lr] = w.w;
        __syncthreads();
#pragma unroll
        for (int k = 0; k < BK; ++k) {
            float4 av = *(const float4*)(&As[k][tm]);
            float4 bv = *(const float4*)(&Bs[k][tn]);
            float ar[4] = {av.x, av.y, av.z, av.w};
            float br[4] = {bv.x, bv.y, bv.z, bv.w};
#pragma unroll
            for (int i = 0; i < 4; ++i)
#pragma unroll
                for (int j = 0; j < 4; ++j)
                    acc[i][j] = fmaf(ar[i], br[j], acc[i][j]);
        }
        __syncthreads();
    }

#pragma unroll
    for (int j = 0; j < 4; ++j) {
        const int col = bn + tn + j;
        if (col < N) {
            const float bj = bias[col];
#pragma unroll
            for (int i = 0; i < 4; ++i)
                C[(size_t)(bm + tm + i) * N + col] = acc[i][j] + bj;
        }
    }
}

// ---------------------------------------------------------------------------
// Fused feature-map + oscillatory scan + attention readout.
// One workgroup per (b,h); 256 threads, thread owns de = d*ETA + n.
// States in registers: K[r][de], S[de] (all threads), V[r][d] (threads de<64).
// ---------------------------------------------------------------------------
__global__ __launch_bounds__(256) void scan_kernel(
    const float* __restrict__ kqv,    // (T*B, H*5*D)
    const float* __restrict__ pbuf,   // (T*B, H*3*ETA)
    const float* __restrict__ term,   // (T, B)
    const float* __restrict__ k_prev, // (B,R,H,DE)
    const float* __restrict__ v_prev, // (B,R,H,D)
    const float* __restrict__ s_prev, // (B,H,DE)
    const float* __restrict__ tick,   // (B,1)
    float* __restrict__ attn,         // (T*B, H*D)
    float* __restrict__ kf, float* __restrict__ vf, float* __restrict__ sf,
    float* __restrict__ tick_out)     // (B,1)
{
    const int bh = blockIdx.x;
    const int b = bh / H_;
    const int h = bh % H_;
    const int de = threadIdx.x;   // 0..255
    const int d = de >> 2;        // de = d*ETA + n
    const int n = de & 3;

    // load initial states
    float K0 = k_prev[((size_t)(b * R_ + 0) * H_ + h) * DE_ + de];
    float K1 = k_prev[((size_t)(b * R_ + 1) * H_ + h) * DE_ + de];
    float K2 = k_prev[((size_t)(b * R_ + 2) * H_ + h) * DE_ + de];
    float K3 = k_prev[((size_t)(b * R_ + 3) * H_ + h) * DE_ + de];
    float S  = s_prev[((size_t)b * H_ + h) * DE_ + de];
    float V0 = 0.f, V1 = 0.f, V2 = 0.f, V3 = 0.f;
    if (de < D_) {
        V0 = v_prev[((size_t)(b * R_ + 0) * H_ + h) * D_ + de];
        V1 = v_prev[((size_t)(b * R_ + 1) * H_ + h) * D_ + de];
        V2 = v_prev[((size_t)(b * R_ + 2) * H_ + h) * D_ + de];
        V3 = v_prev[((size_t)(b * R_ + 3) * H_ + h) * D_ + de];
    }
    const float tk = tick[b];

    __shared__ __align__(16) float s_kqv[5 * D_];  // 320
    __shared__ float s_p[3 * ETA_];                // 12
    __shared__ float s_red[4][5];

    const float PI_F = 3.14159265358979323846f;
    const float om0 = -PI_F, om1 = -PI_F / 3.f, om2 = PI_F / 3.f, om3 = PI_F;

    for (int t = 0; t < T_; ++t) {
        const float* row = kqv + ((size_t)t * B_ + b) * (H_ * 5 * D_) + h * (5 * D_);
        s_kqv[de] = row[de];
        if (de < 64) s_kqv[256 + de] = row[256 + de];
        if (de < 12) s_p[de] = pbuf[((size_t)t * B_ + b) * (H_ * 3 * ETA_) + h * 12 + de];
        __syncthreads();

        const float nt = 1.f - term[(size_t)t * B_ + b];
        const float key = s_kqv[0 * D_ + d];
        const float q   = s_kqv[1 * D_ + d];
        const float gam = s_kqv[4 * D_ + d];
        const float p1 = s_p[0 * ETA_ + n];
        const float p2 = s_p[1 * ETA_ + n];
        const float p3 = s_p[2 * ETA_ + n];

        const float g  = sigmoidf_(gam) * sigmoidf_(p3);          // gamma_e
        const float kg = fmaxf(key, 0.f) * fmaxf(p1, 0.f) * g;    // keys_g
        const float qe = fmaxf(q, 0.f) * fmaxf(p2, 0.f);          // queries_e
        const float dg = (1.f - g) * nt;

        const float tt = tk + (float)(t + 1);
        const float oc0 = cosf(tt * om0);
        const float oc1 = cosf(tt * om1);
        const float oc2 = cosf(tt * om2);
        const float oc3 = cosf(tt * om3);

        // state updates
        S  = dg * S  + kg;
        K0 = dg * K0 + kg * oc0;
        K1 = dg * K1 + kg * oc1;
        K2 = dg * K2 + kg * oc2;
        K3 = dg * K3 + kg * oc3;

        // V path (reads s_kqv before the reuse barrier)
        if (de < D_) {
            const float val = s_kqv[2 * D_ + de];
            const float bet = sigmoidf_(s_kqv[3 * D_ + de]);
            const float vb  = val * bet;
            const float dbv = (1.f - bet) * nt;
            V0 = dbv * V0 + vb * oc0;
            V1 = dbv * V1 + vb * oc1;
            V2 = dbv * V2 + vb * oc2;
            V3 = dbv * V3 + vb * oc3;
        }

        // reductions: kdq[r] = sum_de K[r]*qe ; norm = sum_de S*qe
        float r0 = K0 * qe, r1 = K1 * qe, r2 = K2 * qe, r3 = K3 * qe, r4 = S * qe;
#pragma unroll
        for (int off = 1; off < 64; off <<= 1) {
            r0 += __shfl_xor(r0, off);
            r1 += __shfl_xor(r1, off);
            r2 += __shfl_xor(r2, off);
            r3 += __shfl_xor(r3, off);
            r4 += __shfl_xor(r4, off);
        }
        if ((de & 63) == 0) {
            const int wv = de >> 6;
            s_red[wv][0] = r0; s_red[wv][1] = r1; s_red[wv][2] = r2;
            s_red[wv][3] = r3; s_red[wv][4] = r4;
        }
        __syncthreads();

        if (de < D_) {
            const float kdq0 = s_red[0][0] + s_red[1][0] + s_red[2][0] + s_red[3][0];
            const float kdq1 = s_red[0][1] + s_red[1][1] + s_red[2][1] + s_red[3][1];
            const float kdq2 = s_red[0][2] + s_red[1][2] + s_red[2][2] + s_red[3][2];
            const float kdq3 = s_red[0][3] + s_red[1][3] + s_red[2][3] + s_red[3][3];
            const float nrm  = s_red[0][4] + s_red[1][4] + s_red[2][4] + s_red[3][4];
            const float kv = V0 * kdq0 + V1 * kdq1 + V2 * kdq2 + V3 * kdq3;
            attn[((size_t)t * B_ + b) * (H_ * D_) + h * D_ + de] =
                kv / (2.f * (float)R_ * nrm + EPS_);
        }
        __syncthreads();  // protect s_kqv/s_p/s_red for next iteration
    }

    // final states
    kf[((size_t)(b * R_ + 0) * H_ + h) * DE_ + de] = K0;
    kf[((size_t)(b * R_ + 1) * H_ + h) * DE_ + de] = K1;
    kf[((size_t)(b * R_ + 2) * H_ + h) * DE_ + de] = K2;
    kf[((size_t)(b * R_ + 3) * H_ + h) * DE_ + de] = K3;
    sf[((size_t)b * H_ + h) * DE_ + de] = S;
    if (de < D_) {
        vf[((size_t)(b * R_ + 0) * H_ + h) * D_ + de] = V0;
        vf[((size_t)(b * R_ + 1) * H_ + h) * D_ + de] = V1;
        vf[((size_t)(b * R_ + 2) * H_ + h) * D_ + de] = V2;
        vf[((size_t)(b * R_ + 3) * H_ + h) * D_ + de] = V3;
    }
    if (h == 0 && de == 0) tick_out[b] = tk + (float)T_;
}

// ---------------------------------------------------------------------------
extern "C" void kernel_launch(void* const* d_in, const int* in_sizes, int n_in,
                              void* d_out, int out_size, void* d_ws, size_t ws_size,
                              hipStream_t stream)
{
    const float* inputs = (const float*)d_in[0];
    const float* term   = (const float*)d_in[1];
    const float* k_prev = (const float*)d_in[2];
    const float* v_prev = (const float*)d_in[3];
    const float* s_prev = (const float*)d_in[4];
    const float* tick   = (const float*)d_in[5];
    const float* W_kqv  = (const float*)d_in[6];
    const float* b_kqv  = (const float*)d_in[7];
    const float* W_p    = (const float*)d_in[8];
    const float* b_p    = (const float*)d_in[9];
    const float* W_o    = (const float*)d_in[10];
    const float* b_o    = (const float*)d_in[11];

    float* out = (float*)d_out;                       // (T,B,IN)
    float* kf  = out + (size_t)T_ * B_ * IN_;         // (B,R,H,DE)
    float* vf  = kf  + (size_t)B_ * R_ * H_ * DE_;    // (B,R,H,D)
    float* sf  = vf  + (size_t)B_ * R_ * H_ * D_;     // (B,H,DE)
    float* tick_out = sf + (size_t)B_ * H_ * DE_;     // (B,1)

    float* kqv  = (float*)d_ws;                                   // (4096, 2560)
    float* pbuf = kqv  + (size_t)T_ * B_ * (H_ * 5 * D_);         // (4096, 96)
    float* attn = pbuf + (size_t)T_ * B_ * (H_ * 3 * ETA_);       // (4096, 512)

    const int M = T_ * B_;      // 4096
    const int K = IN_;          // 512

    {   // kqv projection: N = 2560
        dim3 grid((H_ * 5 * D_ + 63) / 64, M / 64);
        sgemm_nt<64, 64, 16><<<grid, 256, 0, stream>>>(inputs, W_kqv, b_kqv, kqv, M, H_ * 5 * D_, K);
    }
    {   // p projection: N = 96
        dim3 grid((H_ * 3 * ETA_ + 63) / 64, M / 64);
        sgemm_nt<64, 64, 16><<<grid, 256, 0, stream>>>(inputs, W_p, b_p, pbuf, M, H_ * 3 * ETA_, K);
    }

    scan_kernel<<<B_ * H_, 256, 0, stream>>>(kqv, pbuf, term, k_prev, v_prev, s_prev,
                                             tick, attn, kf, vf, sf, tick_out);

    {   // output projection: N = IN, K = H*D
        dim3 grid((IN_ + 63) / 64, M / 64);
        sgemm_nt<64, 64, 16><<<grid, 256, 0, stream>>>(attn, W_o, b_o, out, M, IN_, H_ * D_);
    }
}

// Round 2
// 350.598 us; speedup vs baseline: 1.2896x; 1.2896x over previous
//
#include <hip/hip_runtime.h>
#include <math.h>

// Problem constants (match reference)
constexpr int T_ = 128, B_ = 32, IN_ = 512, H_ = 8, D_ = 64, ETA_ = 4, R_ = 4;
constexpr int DE_ = ETA_ * D_;          // 256
constexpr float EPS_ = 1e-5f;

__device__ __forceinline__ float sigmoidf_(float x) { return 1.0f / (1.0f + expf(-x)); }

// ---------------------------------------------------------------------------
// Tiled fp32 GEMM: C(MxN) = A(MxK) @ W(NxK)^T + bias(N)
// 64x64 tile, 256 threads, 4x4 micro-tile per thread. M%64==0, K%16==0; N guarded.
// ---------------------------------------------------------------------------
template <int BM, int BN, int BK>
__global__ __launch_bounds__(256) void sgemm_nt(
    const float* __restrict__ A, const float* __restrict__ W,
    const float* __restrict__ bias, float* __restrict__ C,
    int M, int N, int K)
{
    __shared__ __align__(16) float As[BK][BM + 4];
    __shared__ __align__(16) float Bs[BK][BN + 4];

    const int bm = blockIdx.y * BM;
    const int bn = blockIdx.x * BN;
    const int tid = threadIdx.x;
    const int tm = (tid >> 4) << 2;       // 0..60 step 4
    const int tn = (tid & 15) << 2;       // 0..60 step 4
    const int lr = tid >> 2;              // 0..63 (row in tile)
    const int lc = (tid & 3) << 2;        // 0,4,8,12 (k offset)

    float acc[4][4] = {};

    const float* Aptr = A + (size_t)(bm + lr) * K + lc;
    const int wrow = bn + lr;
    const float* Wptr = W + (size_t)wrow * K + lc;
    const bool wok = (wrow < N);

    for (int k0 = 0; k0 < K; k0 += BK) {
        float4 a = *(const float4*)(Aptr + k0);
        float4 w = make_float4(0.f, 0.f, 0.f, 0.f);
        if (wok) w = *(const float4*)(Wptr + k0);
        As[lc + 0][lr] = a.x; As[lc + 1][lr] = a.y; As[lc + 2][lr] = a.z; As[lc + 3][lr] = a.w;
        Bs[lc + 0][lr] = w.x; Bs[lc + 1][lr] = w.y; Bs[lc + 2][lr] = w.z; Bs[lc + 3][lr] = w.w;
        __syncthreads();
#pragma unroll
        for (int k = 0; k < BK; ++k) {
            float4 av = *(const float4*)(&As[k][tm]);
            float4 bv = *(const float4*)(&Bs[k][tn]);
            float ar[4] = {av.x, av.y, av.z, av.w};
            float br[4] = {bv.x, bv.y, bv.z, bv.w};
#pragma unroll
            for (int i = 0; i < 4; ++i)
#pragma unroll
                for (int j = 0; j < 4; ++j)
                    acc[i][j] = fmaf(ar[i], br[j], acc[i][j]);
        }
        __syncthreads();
    }

#pragma unroll
    for (int j = 0; j < 4; ++j) {
        const int col = bn + tn + j;
        if (col < N) {
            const float bj = bias[col];
#pragma unroll
            for (int i = 0; i < 4; ++i)
                C[(size_t)(bm + tm + i) * N + col] = acc[i][j] + bj;
        }
    }
}

// ---------------------------------------------------------------------------
// Fused feature-map + oscillatory scan + attention readout.
// ONE WAVE per (b,h): lane = d (0..63), each lane owns de = 4d..4d+3.
// All reductions are wave-local __shfl_xor; no LDS, no barriers.
// Next-timestep row is prefetched into registers while computing current.
// ---------------------------------------------------------------------------
__global__ __launch_bounds__(64) void scan_kernel(
    const float* __restrict__ kqv,    // (T*B, H*5*D)
    const float* __restrict__ pbuf,   // (T*B, H*3*ETA)
    const float* __restrict__ term,   // (T, B)
    const float* __restrict__ k_prev, // (B,R,H,DE)
    const float* __restrict__ v_prev, // (B,R,H,D)
    const float* __restrict__ s_prev, // (B,H,DE)
    const float* __restrict__ tick,   // (B,1)
    float* __restrict__ attn,         // (T*B, H*D)
    float* __restrict__ kf, float* __restrict__ vf, float* __restrict__ sf,
    float* __restrict__ tick_out)     // (B,1)
{
    const int bh = blockIdx.x;
    const int b = bh >> 3;            // bh / H_
    const int h = bh & 7;             // bh % H_
    const int d = threadIdx.x;        // 0..63

    // ---- load initial states (vectorized: each lane owns contiguous de 4d..4d+3)
    float K[R_][ETA_], S[ETA_], V[R_];
#pragma unroll
    for (int r = 0; r < R_; ++r) {
        float4 kv4 = *(const float4*)&k_prev[((size_t)(b * R_ + r) * H_ + h) * DE_ + 4 * d];
        K[r][0] = kv4.x; K[r][1] = kv4.y; K[r][2] = kv4.z; K[r][3] = kv4.w;
        V[r] = v_prev[((size_t)(b * R_ + r) * H_ + h) * D_ + d];
    }
    {
        float4 s4 = *(const float4*)&s_prev[((size_t)b * H_ + h) * DE_ + 4 * d];
        S[0] = s4.x; S[1] = s4.y; S[2] = s4.z; S[3] = s4.w;
    }
    const float tk = tick[b];

    const size_t rowstr = (size_t)H_ * 5 * D_;   // 2560
    const float* kqvb = kqv + (size_t)b * rowstr + (size_t)h * (5 * D_);
    const float* pb   = pbuf + (size_t)b * (H_ * 3 * ETA_) + (size_t)h * (3 * ETA_);

    const float PI_F = 3.14159265358979323846f;

    // register prefetch buffers
    float cur[5], nxt[5];
    float curp[12], nxtp[12];
    float curterm, nxtterm;

    {   // t = 0
        const float* rowp = kqvb;
#pragma unroll
        for (int i = 0; i < 5; ++i) cur[i] = rowp[i * D_ + d];
        float4 p0 = *(const float4*)(pb + 0);
        float4 p1 = *(const float4*)(pb + 4);
        float4 p2 = *(const float4*)(pb + 8);
        curp[0] = p0.x; curp[1] = p0.y; curp[2] = p0.z; curp[3] = p0.w;
        curp[4] = p1.x; curp[5] = p1.y; curp[6] = p1.z; curp[7] = p1.w;
        curp[8] = p2.x; curp[9] = p2.y; curp[10] = p2.z; curp[11] = p2.w;
        curterm = term[b];
    }

    for (int t = 0; t < T_; ++t) {
        // ---- prefetch t+1 (clamped) — consumed only at loop end, so the
        // vmcnt wait lands after the compute chain.
        {
            const int tn1 = (t + 1 < T_) ? (t + 1) : (T_ - 1);
            const float* rowp = kqvb + (size_t)tn1 * B_ * rowstr;
#pragma unroll
            for (int i = 0; i < 5; ++i) nxt[i] = rowp[i * D_ + d];
            const float* pr = pb + (size_t)tn1 * B_ * (H_ * 3 * ETA_);
            float4 p0 = *(const float4*)(pr + 0);
            float4 p1 = *(const float4*)(pr + 4);
            float4 p2 = *(const float4*)(pr + 8);
            nxtp[0] = p0.x; nxtp[1] = p0.y; nxtp[2] = p0.z; nxtp[3] = p0.w;
            nxtp[4] = p1.x; nxtp[5] = p1.y; nxtp[6] = p1.z; nxtp[7] = p1.w;
            nxtp[8] = p2.x; nxtp[9] = p2.y; nxtp[10] = p2.z; nxtp[11] = p2.w;
            nxtterm = term[(size_t)tn1 * B_ + b];
        }

        // ---- compute timestep t
        const float nt = 1.f - curterm;
        const float sgam = sigmoidf_(cur[4]);
        const float rk = fmaxf(cur[0], 0.f);
        const float rq = fmaxf(cur[1], 0.f);
        const float sbet = sigmoidf_(cur[3]);
        const float vb = cur[2] * sbet;
        const float dbv = (1.f - sbet) * nt;

        const float tt = tk + (float)(t + 1);
        // omegas = {-pi, -pi/3, pi/3, pi}; cos is even -> 2 distinct values
        const float oc03 = cosf(PI_F * tt);
        const float oc12 = cosf((PI_F / 3.f) * tt);
        const float oc[R_] = {oc03, oc12, oc12, oc03};

        float part0 = 0.f, part1 = 0.f, part2 = 0.f, part3 = 0.f, part4 = 0.f;
#pragma unroll
        for (int n = 0; n < ETA_; ++n) {
            const float g  = sgam * sigmoidf_(curp[8 + n]);
            const float kg = rk * fmaxf(curp[n], 0.f) * g;
            const float qe = rq * fmaxf(curp[4 + n], 0.f);
            const float dg = (1.f - g) * nt;
            S[n]    = fmaf(dg, S[n], kg);
            K[0][n] = fmaf(dg, K[0][n], kg * oc[0]);
            K[1][n] = fmaf(dg, K[1][n], kg * oc[1]);
            K[2][n] = fmaf(dg, K[2][n], kg * oc[2]);
            K[3][n] = fmaf(dg, K[3][n], kg * oc[3]);
            part0 = fmaf(K[0][n], qe, part0);
            part1 = fmaf(K[1][n], qe, part1);
            part2 = fmaf(K[2][n], qe, part2);
            part3 = fmaf(K[3][n], qe, part3);
            part4 = fmaf(S[n],    qe, part4);
        }
#pragma unroll
        for (int r = 0; r < R_; ++r)
            V[r] = fmaf(dbv, V[r], vb * oc[r]);

        // ---- wave-local reduction over all 64 lanes (covers full de=0..255)
#pragma unroll
        for (int off = 1; off < 64; off <<= 1) {
            part0 += __shfl_xor(part0, off);
            part1 += __shfl_xor(part1, off);
            part2 += __shfl_xor(part2, off);
            part3 += __shfl_xor(part3, off);
            part4 += __shfl_xor(part4, off);
        }

        const float kv = V[0] * part0 + V[1] * part1 + V[2] * part2 + V[3] * part3;
        attn[((size_t)t * B_ + b) * (H_ * D_) + h * D_ + d] =
            kv / (2.f * (float)R_ * part4 + EPS_);

        // ---- rotate prefetch buffers
#pragma unroll
        for (int i = 0; i < 5; ++i) cur[i] = nxt[i];
#pragma unroll
        for (int i = 0; i < 12; ++i) curp[i] = nxtp[i];
        curterm = nxtterm;
    }

    // ---- final states
#pragma unroll
    for (int r = 0; r < R_; ++r) {
        *(float4*)&kf[((size_t)(b * R_ + r) * H_ + h) * DE_ + 4 * d] =
            make_float4(K[r][0], K[r][1], K[r][2], K[r][3]);
        vf[((size_t)(b * R_ + r) * H_ + h) * D_ + d] = V[r];
    }
    *(float4*)&sf[((size_t)b * H_ + h) * DE_ + 4 * d] =
        make_float4(S[0], S[1], S[2], S[3]);
    if (h == 0 && d == 0) tick_out[b] = tk + (float)T_;
}

// ---------------------------------------------------------------------------
extern "C" void kernel_launch(void* const* d_in, const int* in_sizes, int n_in,
                              void* d_out, int out_size, void* d_ws, size_t ws_size,
                              hipStream_t stream)
{
    const float* inputs = (const float*)d_in[0];
    const float* term   = (const float*)d_in[1];
    const float* k_prev = (const float*)d_in[2];
    const float* v_prev = (const float*)d_in[3];
    const float* s_prev = (const float*)d_in[4];
    const float* tick   = (const float*)d_in[5];
    const float* W_kqv  = (const float*)d_in[6];
    const float* b_kqv  = (const float*)d_in[7];
    const float* W_p    = (const float*)d_in[8];
    const float* b_p    = (const float*)d_in[9];
    const float* W_o    = (const float*)d_in[10];
    const float* b_o    = (const float*)d_in[11];

    float* out = (float*)d_out;                       // (T,B,IN)
    float* kf  = out + (size_t)T_ * B_ * IN_;         // (B,R,H,DE)
    float* vf  = kf  + (size_t)B_ * R_ * H_ * DE_;    // (B,R,H,D)
    float* sf  = vf  + (size_t)B_ * R_ * H_ * D_;     // (B,H,DE)
    float* tick_out = sf + (size_t)B_ * H_ * DE_;     // (B,1)

    float* kqv  = (float*)d_ws;                                   // (4096, 2560)
    float* pbuf = kqv  + (size_t)T_ * B_ * (H_ * 5 * D_);         // (4096, 96)
    float* attn = pbuf + (size_t)T_ * B_ * (H_ * 3 * ETA_);       // (4096, 512)

    const int M = T_ * B_;      // 4096
    const int K = IN_;          // 512

    {   // kqv projection: N = 2560
        dim3 grid((H_ * 5 * D_ + 63) / 64, M / 64);
        sgemm_nt<64, 64, 16><<<grid, 256, 0, stream>>>(inputs, W_kqv, b_kqv, kqv, M, H_ * 5 * D_, K);
    }
    {   // p projection: N = 96
        dim3 grid((H_ * 3 * ETA_ + 63) / 64, M / 64);
        sgemm_nt<64, 64, 16><<<grid, 256, 0, stream>>>(inputs, W_p, b_p, pbuf, M, H_ * 3 * ETA_, K);
    }

    scan_kernel<<<B_ * H_, 64, 0, stream>>>(kqv, pbuf, term, k_prev, v_prev, s_prev,
                                            tick, attn, kf, vf, sf, tick_out);

    {   // output projection: N = IN, K = H*D
        dim3 grid((IN_ + 63) / 64, M / 64);
        sgemm_nt<64, 64, 16><<<grid, 256, 0, stream>>>(attn, W_o, b_o, out, M, IN_, H_ * D_);
    }
}

// Round 4
// 284.183 us; speedup vs baseline: 1.5910x; 1.2337x over previous
//
#include <hip/hip_runtime.h>
#include <math.h>
#include <stdint.h>

// Problem constants (match reference)
constexpr int T_ = 128, B_ = 32, IN_ = 512, H_ = 8, D_ = 64, ETA_ = 4, R_ = 4;
constexpr int DE_ = ETA_ * D_;          // 256
constexpr float EPS_ = 1e-5f;
constexpr int NKQV = H_ * 5 * D_;       // 2560
constexpr int NP   = H_ * 3 * ETA_;     // 96
constexpr int M_   = T_ * B_;           // 4096

typedef __attribute__((ext_vector_type(8))) short bf16x8;
typedef __attribute__((ext_vector_type(4))) float f32x4;

__device__ __forceinline__ float bf2f(unsigned short u) {
    return __builtin_bit_cast(float, ((unsigned)u) << 16);
}
__device__ __forceinline__ unsigned short f2bf(float f) {
    unsigned u = __builtin_bit_cast(unsigned, f);
    u = (u + 0x7fffu + ((u >> 16) & 1u)) >> 16;   // RNE
    return (unsigned short)u;
}
__device__ __forceinline__ float fsigm(float x) {
    return __fdividef(1.f, 1.f + __expf(-x));
}

// ---------------------------------------------------------------------------
// fp32 -> bf16 cast, 8 elems/thread
// ---------------------------------------------------------------------------
__global__ __launch_bounds__(256) void cast_f32_bf16(
    const float* __restrict__ src, unsigned short* __restrict__ dst, int n8)
{
    int i = blockIdx.x * 256 + threadIdx.x;
    if (i >= n8) return;
    const float4* s = (const float4*)src;
    float4 a = s[2 * i], b = s[2 * i + 1];
    *(ushort4*)(dst + 8 * i)     = make_ushort4(f2bf(a.x), f2bf(a.y), f2bf(a.z), f2bf(a.w));
    *(ushort4*)(dst + 8 * i + 4) = make_ushort4(f2bf(b.x), f2bf(b.y), f2bf(b.z), f2bf(b.w));
}

// ---------------------------------------------------------------------------
// fp32 SGEMM, precision-critical path: C(M,Ntot) = A @ [W1;W2]^T + [b1;b2]
// 128x128 tile, 256 threads, 8x8 micro-tile, BK=16.
// W rows [0,N1) come from W1, [N1,N1+N2) from W2 (fused kqv+p, no concat).
// Register-prefetched staging: global loads for k-step kt+1 issue before the
// FMA loop of kt, so HBM/L2 latency hides under 1024 FMAs.
// ---------------------------------------------------------------------------
__global__ __launch_bounds__(256) void sgemm128(
    const float* __restrict__ A,
    const float* __restrict__ W1, const float* __restrict__ W2,
    const float* __restrict__ bias1, const float* __restrict__ bias2,
    float* __restrict__ C1, float* __restrict__ C2,
    int M, int N1, int N2, int K)
{
    constexpr int BK = 16;
    __shared__ __align__(16) float As[BK][132];
    __shared__ __align__(16) float Bs[BK][132];

    const int Ntot = N1 + N2;
    const int bm = blockIdx.y * 128;
    const int bn = blockIdx.x * 128;
    const int tid = threadIdx.x;
    const int tx = tid & 15, ty = tid >> 4;
    const int tm = ty * 8, tn = tx * 8;

    // staging: thread -> tile row (tid>>1), k-offset (tid&1)*8 ; 8 floats each
    const int srow  = tid >> 1;
    const int skoff = (tid & 1) * 8;
    const float* aP = A + (size_t)(bm + srow) * K + skoff;
    const float* wP;
    {
        const int wrow = bn + srow;
        if (wrow < N1)       wP = W1 + (size_t)wrow * K + skoff;
        else if (wrow < Ntot) wP = W2 + (size_t)(wrow - N1) * K + skoff;
        else                  wP = W1 + skoff;   // OOB clamp (epilogue guards)
    }

    float4 a0, a1, w0, w1;
    a0 = *(const float4*)(aP);     a1 = *(const float4*)(aP + 4);
    w0 = *(const float4*)(wP);     w1 = *(const float4*)(wP + 4);

    float acc[8][8] = {};

    for (int k0 = 0; k0 < K; k0 += BK) {
        __syncthreads();                    // prev k-step finished reading LDS
        As[skoff + 0][srow] = a0.x; As[skoff + 1][srow] = a0.y;
        As[skoff + 2][srow] = a0.z; As[skoff + 3][srow] = a0.w;
        As[skoff + 4][srow] = a1.x; As[skoff + 5][srow] = a1.y;
        As[skoff + 6][srow] = a1.z; As[skoff + 7][srow] = a1.w;
        Bs[skoff + 0][srow] = w0.x; Bs[skoff + 1][srow] = w0.y;
        Bs[skoff + 2][srow] = w0.z; Bs[skoff + 3][srow] = w0.w;
        Bs[skoff + 4][srow] = w1.x; Bs[skoff + 5][srow] = w1.y;
        Bs[skoff + 6][srow] = w1.z; Bs[skoff + 7][srow] = w1.w;
        __syncthreads();
        if (k0 + BK < K) {                  // prefetch next k-step into regs
            a0 = *(const float4*)(aP + k0 + BK);
            a1 = *(const float4*)(aP + k0 + BK + 4);
            w0 = *(const float4*)(wP + k0 + BK);
            w1 = *(const float4*)(wP + k0 + BK + 4);
        }
#pragma unroll
        for (int k = 0; k < BK; ++k) {
            float4 av0 = *(const float4*)&As[k][tm];
            float4 av1 = *(const float4*)&As[k][tm + 4];
            float4 bv0 = *(const float4*)&Bs[k][tn];
            float4 bv1 = *(const float4*)&Bs[k][tn + 4];
            float ar[8] = {av0.x, av0.y, av0.z, av0.w, av1.x, av1.y, av1.z, av1.w};
            float br[8] = {bv0.x, bv0.y, bv0.z, bv0.w, bv1.x, bv1.y, bv1.z, bv1.w};
#pragma unroll
            for (int i = 0; i < 8; ++i)
#pragma unroll
                for (int j = 0; j < 8; ++j)
                    acc[i][j] = fmaf(ar[i], br[j], acc[i][j]);
        }
    }

#pragma unroll
    for (int i = 0; i < 8; ++i) {
        const int row = bm + tm + i;
#pragma unroll
        for (int j = 0; j < 8; ++j) {
            const int col = bn + tn + j;
            if (col < N1)
                C1[(size_t)row * N1 + col] = acc[i][j] + bias1[col];
            else if (col < Ntot)
                C2[(size_t)row * N2 + (col - N1)] = acc[i][j] + bias2[col - N1];
        }
    }
}

// ---------------------------------------------------------------------------
// bf16 MFMA GEMM (m97 structure) — used ONLY for the insensitive output
// projection. 128x128 tile, BK=32, 4 waves, global_load_lds width-16,
// k-group-major 16B granules, double-buffered LDS.
// ---------------------------------------------------------------------------
__device__ __forceinline__ void gl_lds16(const unsigned short* g, unsigned short* l) {
    __builtin_amdgcn_global_load_lds((const __attribute__((address_space(1))) void*)g,
                                     (__attribute__((address_space(3))) void*)l, 16, 0, 0);
}

__global__ __launch_bounds__(256) void gemm_bf16(
    const unsigned short* __restrict__ A,
    const unsigned short* __restrict__ W,
    const float* __restrict__ bias,
    float* __restrict__ C,
    int M, int N, int K)
{
    const int bm = blockIdx.y * 128;
    const int bn = blockIdx.x * 128;
    const int tid = threadIdx.x;
    const int lane = tid & 63;
    const int wid = tid >> 6;
    const int wr = wid >> 1;
    const int wc = wid & 1;

    __shared__ __align__(16) unsigned short As[2][4096];  // 512 granules x 16B
    __shared__ __align__(16) unsigned short Bs[2][4096];

    const int arow = tid & 127;
    const int akg  = tid >> 7;
    const unsigned short* aSrc = A + (size_t)(bm + arow) * K + akg * 8;
    int wrow = bn + arow; if (wrow >= N) wrow = 0;
    const unsigned short* bSrc = W + (size_t)wrow * K + akg * 8;
    const int gb0 = (wid * 64) * 8;
    const int gb1 = (256 + wid * 64) * 8;

    const int fA = (((lane >> 4) * 128) + wr * 64 + (lane & 15)) * 8;
    const int fB = (((lane >> 4) * 128) + wc * 64 + (lane & 15)) * 8;

    f32x4 acc[4][4] = {};
    const int NKT = K >> 5;

    gl_lds16(aSrc, &As[0][gb0]);
    gl_lds16(aSrc + 16, &As[0][gb1]);
    gl_lds16(bSrc, &Bs[0][gb0]);
    gl_lds16(bSrc + 16, &Bs[0][gb1]);
    __syncthreads();

    for (int kt = 0; kt < NKT; ++kt) {
        const int cur = kt & 1;
        if (kt + 1 < NKT) {
            const int ko = (kt + 1) << 5;
            gl_lds16(aSrc + ko, &As[cur ^ 1][gb0]);
            gl_lds16(aSrc + ko + 16, &As[cur ^ 1][gb1]);
            gl_lds16(bSrc + ko, &Bs[cur ^ 1][gb0]);
            gl_lds16(bSrc + ko + 16, &Bs[cur ^ 1][gb1]);
        }
        bf16x8 af[4], bfr[4];
#pragma unroll
        for (int m = 0; m < 4; ++m) af[m] = *(const bf16x8*)&As[cur][fA + m * 128];
#pragma unroll
        for (int n = 0; n < 4; ++n) bfr[n] = *(const bf16x8*)&Bs[cur][fB + n * 128];
#pragma unroll
        for (int m = 0; m < 4; ++m)
#pragma unroll
            for (int n = 0; n < 4; ++n)
                acc[m][n] = __builtin_amdgcn_mfma_f32_16x16x32_bf16(af[m], bfr[n], acc[m][n], 0, 0, 0);
        __syncthreads();
    }

#pragma unroll
    for (int n = 0; n < 4; ++n) {
        const int col = bn + wc * 64 + n * 16 + (lane & 15);
        if (col < N) {
            const float bv = bias[col];
#pragma unroll
            for (int m = 0; m < 4; ++m) {
                const int row0 = bm + wr * 64 + m * 16 + ((lane >> 4) << 2);
#pragma unroll
                for (int j = 0; j < 4; ++j)
                    C[(size_t)(row0 + j) * N + col] = acc[m][n][j] + bv;
            }
        }
    }
}

// ---------------------------------------------------------------------------
// DPP wave64 sum: row_shr 1/2/4/8 (prefix per 16-row), bcast15 (rows 1,3),
// bcast31 (rows 2,3) -> total in lane 63 -> readlane broadcast.
// ---------------------------------------------------------------------------
template <int CTRL, int RM>
__device__ __forceinline__ float dpp_radd(float x) {
    int t = __builtin_amdgcn_update_dpp(0, __builtin_bit_cast(int, x), CTRL, RM, 0xf, true);
    return x + __builtin_bit_cast(float, t);
}
__device__ __forceinline__ float wave_allsum(float x) {
    x = dpp_radd<0x111, 0xf>(x);
    x = dpp_radd<0x112, 0xf>(x);
    x = dpp_radd<0x114, 0xf>(x);
    x = dpp_radd<0x118, 0xf>(x);
    x = dpp_radd<0x142, 0xa>(x);
    x = dpp_radd<0x143, 0xc>(x);
    return __builtin_bit_cast(float, __builtin_amdgcn_readlane(__builtin_bit_cast(int, x), 63));
}

// ---------------------------------------------------------------------------
// Fused scan: one wave per (b,h), lane=d owns de=4d..4d+3. fp32 inputs
// (precision-critical), depth-4 register prefetch, LDS cos table (np-matched
// fp32 omegas + libm cosf), __expf sigmoid. attn written as bf16.
// ---------------------------------------------------------------------------
__global__ __launch_bounds__(64) void scan_kernel(
    const float* __restrict__ kqv,    // (T*B, 2560) f32
    const float* __restrict__ pbuf,   // (T*B, 96) f32
    const float* __restrict__ term,   // (T,B)
    const float* __restrict__ k_prev, const float* __restrict__ v_prev,
    const float* __restrict__ s_prev, const float* __restrict__ tick,
    unsigned short* __restrict__ attn,  // (T*B, 512) bf16
    float* __restrict__ kf, float* __restrict__ vf, float* __restrict__ sf,
    float* __restrict__ tick_out)
{
    const int bh = blockIdx.x;
    const int b = bh >> 3;
    const int h = bh & 7;
    const int d = threadIdx.x;        // 0..63

    float K0[ETA_], K1[ETA_], K2[ETA_], K3[ETA_], S[ETA_];
    float V0, V1, V2, V3;
    {
        float4 k4;
        k4 = *(const float4*)&k_prev[((size_t)(b * R_ + 0) * H_ + h) * DE_ + 4 * d];
        K0[0] = k4.x; K0[1] = k4.y; K0[2] = k4.z; K0[3] = k4.w;
        k4 = *(const float4*)&k_prev[((size_t)(b * R_ + 1) * H_ + h) * DE_ + 4 * d];
        K1[0] = k4.x; K1[1] = k4.y; K1[2] = k4.z; K1[3] = k4.w;
        k4 = *(const float4*)&k_prev[((size_t)(b * R_ + 2) * H_ + h) * DE_ + 4 * d];
        K2[0] = k4.x; K2[1] = k4.y; K2[2] = k4.z; K2[3] = k4.w;
        k4 = *(const float4*)&k_prev[((size_t)(b * R_ + 3) * H_ + h) * DE_ + 4 * d];
        K3[0] = k4.x; K3[1] = k4.y; K3[2] = k4.z; K3[3] = k4.w;
        k4 = *(const float4*)&s_prev[((size_t)b * H_ + h) * DE_ + 4 * d];
        S[0] = k4.x; S[1] = k4.y; S[2] = k4.z; S[3] = k4.w;
        V0 = v_prev[((size_t)(b * R_ + 0) * H_ + h) * D_ + d];
        V1 = v_prev[((size_t)(b * R_ + 1) * H_ + h) * D_ + d];
        V2 = v_prev[((size_t)(b * R_ + 2) * H_ + h) * D_ + d];
        V3 = v_prev[((size_t)(b * R_ + 3) * H_ + h) * D_ + d];
    }
    const float tk = tick[b];

    // cos table; omegas match np.float32(linspace(-pi,pi,4)) exactly.
    __shared__ float s_oc[T_][2];
    {
        const float om03 = 3.14159265358979323846f;   // rounds to 0x40490FDB
        const float om12 = 1.04719755119659774615f;   // rounds to 0x3F860A92
#pragma unroll
        for (int i = 0; i < 2; ++i) {
            const int t = d + i * 64;
            const float tt = tk + (float)(t + 1);
            s_oc[t][0] = cosf(om03 * tt);
            s_oc[t][1] = cosf(om12 * tt);
        }
    }
    __syncthreads();

    struct RowT { float c[5]; float p[12]; float tm; };

    auto loadrow = [&](RowT& r, int t) {
        const float* kq = kqv + ((size_t)t * B_ + b) * NKQV + h * 320;
#pragma unroll
        for (int i = 0; i < 5; ++i) r.c[i] = kq[i * 64 + d];
        const float* pr = pbuf + ((size_t)t * B_ + b) * NP + h * 12;
        float4 q0 = *(const float4*)pr;
        float4 q1 = *(const float4*)(pr + 4);
        float4 q2 = *(const float4*)(pr + 8);
        r.p[0] = q0.x; r.p[1] = q0.y; r.p[2] = q0.z; r.p[3] = q0.w;
        r.p[4] = q1.x; r.p[5] = q1.y; r.p[6] = q1.z; r.p[7] = q1.w;
        r.p[8] = q2.x; r.p[9] = q2.y; r.p[10] = q2.z; r.p[11] = q2.w;
        r.tm = term[(size_t)t * B_ + b];
    };

    auto computeT = [&](int t, RowT& r) {
        const float oc03 = s_oc[t][0];
        const float oc12 = s_oc[t][1];
        const float nt = 1.f - r.tm;
        const float sgam = fsigm(r.c[4]);
        const float rk = fmaxf(r.c[0], 0.f);
        const float rq = fmaxf(r.c[1], 0.f);
        const float sbet = fsigm(r.c[3]);
        const float vb = r.c[2] * sbet;
        const float dbv = (1.f - sbet) * nt;

        float p0 = 0.f, p1s = 0.f, p2s = 0.f, p3s = 0.f, p4s = 0.f;
#pragma unroll
        for (int n = 0; n < ETA_; ++n) {
            const float g  = sgam * fsigm(r.p[8 + n]);
            const float kg = rk * fmaxf(r.p[n], 0.f) * g;
            const float qe = rq * fmaxf(r.p[4 + n], 0.f);
            const float dg = (1.f - g) * nt;
            S[n]  = fmaf(dg, S[n],  kg);
            K0[n] = fmaf(dg, K0[n], kg * oc03);
            K1[n] = fmaf(dg, K1[n], kg * oc12);
            K2[n] = fmaf(dg, K2[n], kg * oc12);
            K3[n] = fmaf(dg, K3[n], kg * oc03);
            p0  = fmaf(K0[n], qe, p0);
            p1s = fmaf(K1[n], qe, p1s);
            p2s = fmaf(K2[n], qe, p2s);
            p3s = fmaf(K3[n], qe, p3s);
            p4s = fmaf(S[n],  qe, p4s);
        }
        V0 = fmaf(dbv, V0, vb * oc03);
        V1 = fmaf(dbv, V1, vb * oc12);
        V2 = fmaf(dbv, V2, vb * oc12);
        V3 = fmaf(dbv, V3, vb * oc03);

        const float kdq0 = wave_allsum(p0);
        const float kdq1 = wave_allsum(p1s);
        const float kdq2 = wave_allsum(p2s);
        const float kdq3 = wave_allsum(p3s);
        const float nrm  = wave_allsum(p4s);

        const float kv = V0 * kdq0 + V1 * kdq1 + V2 * kdq2 + V3 * kdq3;
        attn[((size_t)t * B_ + b) * (H_ * D_) + h * D_ + d] =
            f2bf(__fdividef(kv, 2.f * (float)R_ * nrm + EPS_));
    };

    RowT ra, rb, rc, rd;
    loadrow(ra, 0); loadrow(rb, 1); loadrow(rc, 2); loadrow(rd, 3);

    for (int t = 0; t < T_; t += 4) {
        computeT(t, ra);     if (t + 4 < T_) loadrow(ra, t + 4);
        computeT(t + 1, rb); if (t + 5 < T_) loadrow(rb, t + 5);
        computeT(t + 2, rc); if (t + 6 < T_) loadrow(rc, t + 6);
        computeT(t + 3, rd); if (t + 7 < T_) loadrow(rd, t + 7);
    }

    *(float4*)&kf[((size_t)(b * R_ + 0) * H_ + h) * DE_ + 4 * d] = make_float4(K0[0], K0[1], K0[2], K0[3]);
    *(float4*)&kf[((size_t)(b * R_ + 1) * H_ + h) * DE_ + 4 * d] = make_float4(K1[0], K1[1], K1[2], K1[3]);
    *(float4*)&kf[((size_t)(b * R_ + 2) * H_ + h) * DE_ + 4 * d] = make_float4(K2[0], K2[1], K2[2], K2[3]);
    *(float4*)&kf[((size_t)(b * R_ + 3) * H_ + h) * DE_ + 4 * d] = make_float4(K3[0], K3[1], K3[2], K3[3]);
    *(float4*)&sf[((size_t)b * H_ + h) * DE_ + 4 * d] = make_float4(S[0], S[1], S[2], S[3]);
    vf[((size_t)(b * R_ + 0) * H_ + h) * D_ + d] = V0;
    vf[((size_t)(b * R_ + 1) * H_ + h) * D_ + d] = V1;
    vf[((size_t)(b * R_ + 2) * H_ + h) * D_ + d] = V2;
    vf[((size_t)(b * R_ + 3) * H_ + h) * D_ + d] = V3;
    if (h == 0 && d == 0) tick_out[b] = tk + (float)T_;
}

// ---------------------------------------------------------------------------
extern "C" void kernel_launch(void* const* d_in, const int* in_sizes, int n_in,
                              void* d_out, int out_size, void* d_ws, size_t ws_size,
                              hipStream_t stream)
{
    const float* inputs = (const float*)d_in[0];
    const float* term   = (const float*)d_in[1];
    const float* k_prev = (const float*)d_in[2];
    const float* v_prev = (const float*)d_in[3];
    const float* s_prev = (const float*)d_in[4];
    const float* tick   = (const float*)d_in[5];
    const float* W_kqv  = (const float*)d_in[6];
    const float* b_kqv  = (const float*)d_in[7];
    const float* W_p    = (const float*)d_in[8];
    const float* b_p    = (const float*)d_in[9];
    const float* W_o    = (const float*)d_in[10];
    const float* b_o    = (const float*)d_in[11];

    float* out = (float*)d_out;                       // (T,B,IN)
    float* kf  = out + (size_t)T_ * B_ * IN_;
    float* vf  = kf  + (size_t)B_ * R_ * H_ * DE_;
    float* sf  = vf  + (size_t)B_ * R_ * H_ * D_;
    float* tick_out = sf + (size_t)B_ * H_ * DE_;

    // workspace: 48.2 MB total (proven-fit: R2 used 52 MB)
    float* kqv_f  = (float*)d_ws;                                  // 4096x2560 f32
    float* p_f    = kqv_f + (size_t)M_ * NKQV;                     // 4096x96 f32
    unsigned short* attn_bf = (unsigned short*)(p_f + (size_t)M_ * NP);  // 4096x512 bf16
    unsigned short* Wo_bf   = attn_bf + (size_t)M_ * IN_;          // 512x512 bf16

    {   // cast W_o to bf16 (output projection is precision-insensitive)
        int n8 = (IN_ * (H_ * D_)) / 8;
        cast_f32_bf16<<<(n8 + 255) / 256, 256, 0, stream>>>(W_o, Wo_bf, n8);
    }

    {   // fused kqv+p projection in fp32 (precision-critical): Ntot = 2656
        dim3 grid((NKQV + NP + 127) / 128, M_ / 128);   // 21 x 32
        sgemm128<<<grid, 256, 0, stream>>>(inputs, W_kqv, W_p, b_kqv, b_p,
                                           kqv_f, p_f, M_, NKQV, NP, IN_);
    }

    scan_kernel<<<B_ * H_, 64, 0, stream>>>(kqv_f, p_f, term, k_prev, v_prev,
                                            s_prev, tick, attn_bf, kf, vf, sf, tick_out);

    {   // output projection: bf16 MFMA, N = 512, K = 512
        dim3 grid(IN_ / 128, M_ / 128);                 // 4 x 32
        gemm_bf16<<<grid, 256, 0, stream>>>(attn_bf, Wo_bf, b_o, out, M_, IN_, H_ * D_);
    }
}

// Round 5
// 221.902 us; speedup vs baseline: 2.0376x; 1.2807x over previous
//
#include <hip/hip_runtime.h>
#include <math.h>
#include <stdint.h>

// Problem constants (match reference)
constexpr int T_ = 128, B_ = 32, IN_ = 512, H_ = 8, D_ = 64, ETA_ = 4, R_ = 4;
constexpr int DE_ = ETA_ * D_;          // 256
constexpr float EPS_ = 1e-5f;
constexpr int NKQV = H_ * 5 * D_;       // 2560
constexpr int NP   = H_ * 3 * ETA_;     // 96
constexpr int M_   = T_ * B_;           // 4096

typedef __attribute__((ext_vector_type(8))) short bf16x8;
typedef __attribute__((ext_vector_type(4))) float f32x4;

__device__ __forceinline__ float bf2f(unsigned short u) {
    return __builtin_bit_cast(float, ((unsigned)u) << 16);
}
__device__ __forceinline__ unsigned short f2bf(float f) {
    unsigned u = __builtin_bit_cast(unsigned, f);
    u = (u + 0x7fffu + ((u >> 16) & 1u)) >> 16;   // RNE
    return (unsigned short)u;
}
__device__ __forceinline__ float fsigm(float x) {
    return __fdividef(1.f, 1.f + __expf(-x));
}

// ---------------------------------------------------------------------------
// fp32 -> bf16 cast, 8 elems/thread (for precision-insensitive W_o)
// ---------------------------------------------------------------------------
__global__ __launch_bounds__(256) void cast_f32_bf16(
    const float* __restrict__ src, unsigned short* __restrict__ dst, int n8)
{
    int i = blockIdx.x * 256 + threadIdx.x;
    if (i >= n8) return;
    const float4* s = (const float4*)src;
    float4 a = s[2 * i], b = s[2 * i + 1];
    *(ushort4*)(dst + 8 * i)     = make_ushort4(f2bf(a.x), f2bf(a.y), f2bf(a.z), f2bf(a.w));
    *(ushort4*)(dst + 8 * i + 4) = make_ushort4(f2bf(b.x), f2bf(b.y), f2bf(b.z), f2bf(b.w));
}

// ---------------------------------------------------------------------------
// fp32 -> split (hi,lo) bf16. Source rows of 512 floats. Per element:
//   hi = bf16(x); lo = bf16(x - hi)   (x-hi is exact in f32)
// dst row stride K3 shorts; hi at col c, lo at c+off_lo, optional hi dup at
// c+off_hi2 (off_hi2 < 0 -> skip). Thread = 4 elems.
// ---------------------------------------------------------------------------
__global__ __launch_bounds__(256) void cast_split(
    const float* __restrict__ src, unsigned short* __restrict__ dst,
    int n4, int K3, int off_lo, int off_hi2)
{
    int i = blockIdx.x * 256 + threadIdx.x;
    if (i >= n4) return;
    const int r = i >> 7;              // Ksrc = 512 -> 128 float4 per row
    const int c = (i & 127) << 2;
    float4 x = *(const float4*)(src + (size_t)r * 512 + c);
    ushort4 hi = make_ushort4(f2bf(x.x), f2bf(x.y), f2bf(x.z), f2bf(x.w));
    ushort4 lo = make_ushort4(f2bf(x.x - bf2f(hi.x)), f2bf(x.y - bf2f(hi.y)),
                              f2bf(x.z - bf2f(hi.z)), f2bf(x.w - bf2f(hi.w)));
    unsigned short* dr = dst + (size_t)r * K3 + c;
    *(ushort4*)dr = hi;
    *(ushort4*)(dr + off_lo) = lo;
    if (off_hi2 >= 0) *(ushort4*)(dr + off_hi2) = hi;
}

// ---------------------------------------------------------------------------
// bf16 MFMA GEMM (m97 structure): C = A(M,sA) @ W(Ntot,sW)^T + bias, f32 out.
// 128x128 tile, BK=32, 4 waves, global_load_lds width-16, double-buffered.
// Column routing: col < N1 -> C1/bias1 else C2/bias2 (fused kqv+p outputs).
// SPLIT: K spans 3 blocks of 512 pairing A2=[A_hi|A_lo] (stride 1024) with
// W2=[W_hi|W_lo|W_hi] (stride 1536): hi*hi + hi*lo + lo*hi  (3xTF32-style).
// ---------------------------------------------------------------------------
__device__ __forceinline__ void gl_lds16(const unsigned short* g, unsigned short* l) {
    __builtin_amdgcn_global_load_lds((const __attribute__((address_space(1))) void*)g,
                                     (__attribute__((address_space(3))) void*)l, 16, 0, 0);
}
__device__ __forceinline__ int ko_map(bool split, int ko) {
    return (split && ko >= 512) ? ko - 512 : ko;
}

template <bool SPLIT>
__global__ __launch_bounds__(256) void gemm_bf16(
    const unsigned short* __restrict__ A,
    const unsigned short* __restrict__ W,
    const float* __restrict__ bias1, const float* __restrict__ bias2,
    float* __restrict__ C1, float* __restrict__ C2,
    int M, int N1, int N2, int K, int sA, int sW)
{
    const int Ntot = N1 + N2;
    const int bm = blockIdx.y * 128;
    const int bn = blockIdx.x * 128;
    const int tid = threadIdx.x;
    const int lane = tid & 63;
    const int wid = tid >> 6;
    const int wr = wid >> 1;
    const int wc = wid & 1;

    __shared__ __align__(16) unsigned short As[2][4096];  // 512 granules x 16B
    __shared__ __align__(16) unsigned short Bs[2][4096];

    const int arow = tid & 127;
    const int akg  = tid >> 7;
    const unsigned short* aSrc = A + (size_t)(bm + arow) * sA + akg * 8;
    int wrow = bn + arow; if (wrow >= Ntot) wrow = 0;
    const unsigned short* bSrc = W + (size_t)wrow * sW + akg * 8;
    const int gb0 = (wid * 64) * 8;
    const int gb1 = (256 + wid * 64) * 8;

    const int fA = (((lane >> 4) * 128) + wr * 64 + (lane & 15)) * 8;
    const int fB = (((lane >> 4) * 128) + wc * 64 + (lane & 15)) * 8;

    f32x4 acc[4][4] = {};
    const int NKT = K >> 5;

    gl_lds16(aSrc, &As[0][gb0]);
    gl_lds16(aSrc + 16, &As[0][gb1]);
    gl_lds16(bSrc, &Bs[0][gb0]);
    gl_lds16(bSrc + 16, &Bs[0][gb1]);
    __syncthreads();

    for (int kt = 0; kt < NKT; ++kt) {
        const int cur = kt & 1;
        if (kt + 1 < NKT) {
            const int ko  = (kt + 1) << 5;
            const int koA = ko_map(SPLIT, ko);
            gl_lds16(aSrc + koA, &As[cur ^ 1][gb0]);
            gl_lds16(aSrc + koA + 16, &As[cur ^ 1][gb1]);
            gl_lds16(bSrc + ko, &Bs[cur ^ 1][gb0]);
            gl_lds16(bSrc + ko + 16, &Bs[cur ^ 1][gb1]);
        }
        bf16x8 af[4], bfr[4];
#pragma unroll
        for (int m = 0; m < 4; ++m) af[m] = *(const bf16x8*)&As[cur][fA + m * 128];
#pragma unroll
        for (int n = 0; n < 4; ++n) bfr[n] = *(const bf16x8*)&Bs[cur][fB + n * 128];
#pragma unroll
        for (int m = 0; m < 4; ++m)
#pragma unroll
            for (int n = 0; n < 4; ++n)
                acc[m][n] = __builtin_amdgcn_mfma_f32_16x16x32_bf16(af[m], bfr[n], acc[m][n], 0, 0, 0);
        __syncthreads();
    }

    // epilogue: C/D layout col=lane&15, row=(lane>>4)*4+j  [m89]
#pragma unroll
    for (int n = 0; n < 4; ++n) {
        const int col = bn + wc * 64 + n * 16 + (lane & 15);
        if (col < Ntot) {
            const float bv = (col < N1) ? bias1[col] : bias2[col - N1];
#pragma unroll
            for (int m = 0; m < 4; ++m) {
                const int row0 = bm + wr * 64 + m * 16 + ((lane >> 4) << 2);
#pragma unroll
                for (int j = 0; j < 4; ++j) {
                    const float v = acc[m][n][j] + bv;
                    const int row = row0 + j;
                    if (col < N1)
                        C1[(size_t)row * N1 + col] = v;
                    else
                        C2[(size_t)row * N2 + (col - N1)] = v;
                }
            }
        }
    }
}

// ---------------------------------------------------------------------------
// DPP wave64 sum: row_shr 1/2/4/8, bcast15, bcast31 -> lane 63 -> readlane.
// ---------------------------------------------------------------------------
template <int CTRL, int RM>
__device__ __forceinline__ float dpp_radd(float x) {
    int t = __builtin_amdgcn_update_dpp(0, __builtin_bit_cast(int, x), CTRL, RM, 0xf, true);
    return x + __builtin_bit_cast(float, t);
}
__device__ __forceinline__ float wave_allsum(float x) {
    x = dpp_radd<0x111, 0xf>(x);
    x = dpp_radd<0x112, 0xf>(x);
    x = dpp_radd<0x114, 0xf>(x);
    x = dpp_radd<0x118, 0xf>(x);
    x = dpp_radd<0x142, 0xa>(x);
    x = dpp_radd<0x143, 0xc>(x);
    return __builtin_bit_cast(float, __builtin_amdgcn_readlane(__builtin_bit_cast(int, x), 63));
}

// ---------------------------------------------------------------------------
// Fused scan: one wave per (b,h), lane=d owns de=4d..4d+3. fp32 inputs
// (precision-critical), depth-4 register prefetch, LDS cos table, __expf
// sigmoid. attn written as bf16.
// ---------------------------------------------------------------------------
__global__ __launch_bounds__(64) void scan_kernel(
    const float* __restrict__ kqv,    // (T*B, 2560) f32
    const float* __restrict__ pbuf,   // (T*B, 96) f32
    const float* __restrict__ term,   // (T,B)
    const float* __restrict__ k_prev, const float* __restrict__ v_prev,
    const float* __restrict__ s_prev, const float* __restrict__ tick,
    unsigned short* __restrict__ attn,  // (T*B, 512) bf16
    float* __restrict__ kf, float* __restrict__ vf, float* __restrict__ sf,
    float* __restrict__ tick_out)
{
    const int bh = blockIdx.x;
    const int b = bh >> 3;
    const int h = bh & 7;
    const int d = threadIdx.x;        // 0..63

    float K0[ETA_], K1[ETA_], K2[ETA_], K3[ETA_], S[ETA_];
    float V0, V1, V2, V3;
    {
        float4 k4;
        k4 = *(const float4*)&k_prev[((size_t)(b * R_ + 0) * H_ + h) * DE_ + 4 * d];
        K0[0] = k4.x; K0[1] = k4.y; K0[2] = k4.z; K0[3] = k4.w;
        k4 = *(const float4*)&k_prev[((size_t)(b * R_ + 1) * H_ + h) * DE_ + 4 * d];
        K1[0] = k4.x; K1[1] = k4.y; K1[2] = k4.z; K1[3] = k4.w;
        k4 = *(const float4*)&k_prev[((size_t)(b * R_ + 2) * H_ + h) * DE_ + 4 * d];
        K2[0] = k4.x; K2[1] = k4.y; K2[2] = k4.z; K2[3] = k4.w;
        k4 = *(const float4*)&k_prev[((size_t)(b * R_ + 3) * H_ + h) * DE_ + 4 * d];
        K3[0] = k4.x; K3[1] = k4.y; K3[2] = k4.z; K3[3] = k4.w;
        k4 = *(const float4*)&s_prev[((size_t)b * H_ + h) * DE_ + 4 * d];
        S[0] = k4.x; S[1] = k4.y; S[2] = k4.z; S[3] = k4.w;
        V0 = v_prev[((size_t)(b * R_ + 0) * H_ + h) * D_ + d];
        V1 = v_prev[((size_t)(b * R_ + 1) * H_ + h) * D_ + d];
        V2 = v_prev[((size_t)(b * R_ + 2) * H_ + h) * D_ + d];
        V3 = v_prev[((size_t)(b * R_ + 3) * H_ + h) * D_ + d];
    }
    const float tk = tick[b];

    // cos table; omegas match np.float32(linspace(-pi,pi,4)) exactly.
    __shared__ float s_oc[T_][2];
    {
        const float om03 = 3.14159265358979323846f;   // 0x40490FDB
        const float om12 = 1.04719755119659774615f;   // 0x3F860A92
#pragma unroll
        for (int i = 0; i < 2; ++i) {
            const int t = d + i * 64;
            const float tt = tk + (float)(t + 1);
            s_oc[t][0] = cosf(om03 * tt);
            s_oc[t][1] = cosf(om12 * tt);
        }
    }
    __syncthreads();

    struct RowT { float c[5]; float p[12]; float tm; };

    auto loadrow = [&](RowT& r, int t) {
        const float* kq = kqv + ((size_t)t * B_ + b) * NKQV + h * 320;
#pragma unroll
        for (int i = 0; i < 5; ++i) r.c[i] = kq[i * 64 + d];
        const float* pr = pbuf + ((size_t)t * B_ + b) * NP + h * 12;
        float4 q0 = *(const float4*)pr;
        float4 q1 = *(const float4*)(pr + 4);
        float4 q2 = *(const float4*)(pr + 8);
        r.p[0] = q0.x; r.p[1] = q0.y; r.p[2] = q0.z; r.p[3] = q0.w;
        r.p[4] = q1.x; r.p[5] = q1.y; r.p[6] = q1.z; r.p[7] = q1.w;
        r.p[8] = q2.x; r.p[9] = q2.y; r.p[10] = q2.z; r.p[11] = q2.w;
        r.tm = term[(size_t)t * B_ + b];
    };

    auto computeT = [&](int t, RowT& r) {
        const float oc03 = s_oc[t][0];
        const float oc12 = s_oc[t][1];
        const float nt = 1.f - r.tm;
        const float sgam = fsigm(r.c[4]);
        const float rk = fmaxf(r.c[0], 0.f);
        const float rq = fmaxf(r.c[1], 0.f);
        const float sbet = fsigm(r.c[3]);
        const float vb = r.c[2] * sbet;
        const float dbv = (1.f - sbet) * nt;

        float p0 = 0.f, p1s = 0.f, p2s = 0.f, p3s = 0.f, p4s = 0.f;
#pragma unroll
        for (int n = 0; n < ETA_; ++n) {
            const float g  = sgam * fsigm(r.p[8 + n]);
            const float kg = rk * fmaxf(r.p[n], 0.f) * g;
            const float qe = rq * fmaxf(r.p[4 + n], 0.f);
            const float dg = (1.f - g) * nt;
            S[n]  = fmaf(dg, S[n],  kg);
            K0[n] = fmaf(dg, K0[n], kg * oc03);
            K1[n] = fmaf(dg, K1[n], kg * oc12);
            K2[n] = fmaf(dg, K2[n], kg * oc12);
            K3[n] = fmaf(dg, K3[n], kg * oc03);
            p0  = fmaf(K0[n], qe, p0);
            p1s = fmaf(K1[n], qe, p1s);
            p2s = fmaf(K2[n], qe, p2s);
            p3s = fmaf(K3[n], qe, p3s);
            p4s = fmaf(S[n],  qe, p4s);
        }
        V0 = fmaf(dbv, V0, vb * oc03);
        V1 = fmaf(dbv, V1, vb * oc12);
        V2 = fmaf(dbv, V2, vb * oc12);
        V3 = fmaf(dbv, V3, vb * oc03);

        const float kdq0 = wave_allsum(p0);
        const float kdq1 = wave_allsum(p1s);
        const float kdq2 = wave_allsum(p2s);
        const float kdq3 = wave_allsum(p3s);
        const float nrm  = wave_allsum(p4s);

        const float kv = V0 * kdq0 + V1 * kdq1 + V2 * kdq2 + V3 * kdq3;
        attn[((size_t)t * B_ + b) * (H_ * D_) + h * D_ + d] =
            f2bf(__fdividef(kv, 2.f * (float)R_ * nrm + EPS_));
    };

    RowT ra, rb, rc, rd;
    loadrow(ra, 0); loadrow(rb, 1); loadrow(rc, 2); loadrow(rd, 3);

    for (int t = 0; t < T_; t += 4) {
        computeT(t, ra);     if (t + 4 < T_) loadrow(ra, t + 4);
        computeT(t + 1, rb); if (t + 5 < T_) loadrow(rb, t + 5);
        computeT(t + 2, rc); if (t + 6 < T_) loadrow(rc, t + 6);
        computeT(t + 3, rd); if (t + 7 < T_) loadrow(rd, t + 7);
    }

    *(float4*)&kf[((size_t)(b * R_ + 0) * H_ + h) * DE_ + 4 * d] = make_float4(K0[0], K0[1], K0[2], K0[3]);
    *(float4*)&kf[((size_t)(b * R_ + 1) * H_ + h) * DE_ + 4 * d] = make_float4(K1[0], K1[1], K1[2], K1[3]);
    *(float4*)&kf[((size_t)(b * R_ + 2) * H_ + h) * DE_ + 4 * d] = make_float4(K2[0], K2[1], K2[2], K2[3]);
    *(float4*)&kf[((size_t)(b * R_ + 3) * H_ + h) * DE_ + 4 * d] = make_float4(K3[0], K3[1], K3[2], K3[3]);
    *(float4*)&sf[((size_t)b * H_ + h) * DE_ + 4 * d] = make_float4(S[0], S[1], S[2], S[3]);
    vf[((size_t)(b * R_ + 0) * H_ + h) * D_ + d] = V0;
    vf[((size_t)(b * R_ + 1) * H_ + h) * D_ + d] = V1;
    vf[((size_t)(b * R_ + 2) * H_ + h) * D_ + d] = V2;
    vf[((size_t)(b * R_ + 3) * H_ + h) * D_ + d] = V3;
    if (h == 0 && d == 0) tick_out[b] = tk + (float)T_;
}

// ---------------------------------------------------------------------------
extern "C" void kernel_launch(void* const* d_in, const int* in_sizes, int n_in,
                              void* d_out, int out_size, void* d_ws, size_t ws_size,
                              hipStream_t stream)
{
    const float* inputs = (const float*)d_in[0];
    const float* term   = (const float*)d_in[1];
    const float* k_prev = (const float*)d_in[2];
    const float* v_prev = (const float*)d_in[3];
    const float* s_prev = (const float*)d_in[4];
    const float* tick   = (const float*)d_in[5];
    const float* W_kqv  = (const float*)d_in[6];
    const float* b_kqv  = (const float*)d_in[7];
    const float* W_p    = (const float*)d_in[8];
    const float* b_p    = (const float*)d_in[9];
    const float* W_o    = (const float*)d_in[10];
    const float* b_o    = (const float*)d_in[11];

    float* out = (float*)d_out;                       // (T,B,IN)
    float* kf  = out + (size_t)T_ * B_ * IN_;
    float* vf  = kf  + (size_t)B_ * R_ * H_ * DE_;
    float* sf  = vf  + (size_t)B_ * R_ * H_ * D_;
    float* tick_out = sf + (size_t)B_ * H_ * DE_;

    // workspace (~65 MB)
    float* kqv_f  = (float*)d_ws;                                   // 4096x2560 f32  41.9MB
    float* p_f    = kqv_f + (size_t)M_ * NKQV;                      // 4096x96 f32     1.6MB
    unsigned short* attn_bf = (unsigned short*)(p_f + (size_t)M_ * NP);   // 4096x512 bf16 4.2MB
    unsigned short* Wo_bf   = attn_bf + (size_t)M_ * IN_;           // 512x512 bf16    0.5MB
    unsigned short* A2      = Wo_bf + (size_t)IN_ * (H_ * D_);      // 4096x1024 [hi|lo] 8.4MB
    unsigned short* W2      = A2 + (size_t)M_ * 1024;               // 2656x1536 [hi|lo|hi] 8.2MB

    {   // splits + plain cast
        int n4 = M_ * 128;      // inputs: 4096 rows
        cast_split<<<(n4 + 255) / 256, 256, 0, stream>>>(inputs, A2, n4, 1024, 512, -1);
        n4 = NKQV * 128;        // W_kqv: 2560 rows
        cast_split<<<(n4 + 255) / 256, 256, 0, stream>>>(W_kqv, W2, n4, 1536, 512, 1024);
        n4 = NP * 128;          // W_p: 96 rows
        cast_split<<<(n4 + 255) / 256, 256, 0, stream>>>(W_p, W2 + (size_t)NKQV * 1536, n4, 1536, 512, 1024);
        int n8 = (IN_ * (H_ * D_)) / 8;
        cast_f32_bf16<<<(n8 + 255) / 256, 256, 0, stream>>>(W_o, Wo_bf, n8);
    }

    {   // fused kqv+p projection, split-bf16 (fp32-class precision): Ntot=2656, K'=1536
        dim3 grid((NKQV + NP + 127) / 128, M_ / 128);   // 21 x 32
        gemm_bf16<true><<<grid, 256, 0, stream>>>(A2, W2, b_kqv, b_p,
                                                  kqv_f, p_f, M_, NKQV, NP,
                                                  1536, 1024, 1536);
    }

    scan_kernel<<<B_ * H_, 64, 0, stream>>>(kqv_f, p_f, term, k_prev, v_prev,
                                            s_prev, tick, attn_bf, kf, vf, sf, tick_out);

    {   // output projection: plain bf16 MFMA, N=512, K=512
        dim3 grid(IN_ / 128, M_ / 128);                 // 4 x 32
        gemm_bf16<false><<<grid, 256, 0, stream>>>(attn_bf, Wo_bf, b_o, b_o,
                                                   out, nullptr, M_, IN_, 0,
                                                   512, 512, 512);
    }
}

// Round 6
// 163.456 us; speedup vs baseline: 2.7662x; 1.3576x over previous
//
#include <hip/hip_runtime.h>
#include <math.h>
#include <stdint.h>

// Problem constants (match reference)
constexpr int T_ = 128, B_ = 32, IN_ = 512, H_ = 8, D_ = 64, ETA_ = 4, R_ = 4;
constexpr int DE_ = ETA_ * D_;          // 256
constexpr float EPS_ = 1e-5f;
constexpr int NKQV = H_ * 5 * D_;       // 2560
constexpr int NP   = H_ * 3 * ETA_;     // 96
constexpr int M_   = T_ * B_;           // 4096
constexpr int NCH  = 8;                 // scan chunks
constexpr int CH   = T_ / NCH;          // 16 steps per chunk
constexpr int BH_  = B_ * H_;           // 256

typedef __attribute__((ext_vector_type(8))) short bf16x8;
typedef __attribute__((ext_vector_type(4))) float f32x4;

__device__ __forceinline__ float bf2f(unsigned short u) {
    return __builtin_bit_cast(float, ((unsigned)u) << 16);
}
__device__ __forceinline__ unsigned short f2bf(float f) {
    unsigned u = __builtin_bit_cast(unsigned, f);
    u = (u + 0x7fffu + ((u >> 16) & 1u)) >> 16;   // RNE
    return (unsigned short)u;
}
__device__ __forceinline__ float fsigm(float x) {
    return __fdividef(1.f, 1.f + __expf(-x));
}

// ---------------------------------------------------------------------------
// fp32 -> bf16 cast, 8 elems/thread (precision-insensitive W_o)
// ---------------------------------------------------------------------------
__global__ __launch_bounds__(256) void cast_f32_bf16(
    const float* __restrict__ src, unsigned short* __restrict__ dst, int n8)
{
    int i = blockIdx.x * 256 + threadIdx.x;
    if (i >= n8) return;
    const float4* s = (const float4*)src;
    float4 a = s[2 * i], b = s[2 * i + 1];
    *(ushort4*)(dst + 8 * i)     = make_ushort4(f2bf(a.x), f2bf(a.y), f2bf(a.z), f2bf(a.w));
    *(ushort4*)(dst + 8 * i + 4) = make_ushort4(f2bf(b.x), f2bf(b.y), f2bf(b.z), f2bf(b.w));
}

// ---------------------------------------------------------------------------
// fp32 -> split (hi,lo) bf16.  hi = bf16(x); lo = bf16(x - hi).
// dst row stride K3 shorts; hi at c, lo at c+off_lo, dup hi at c+off_hi2 (>=0).
// ---------------------------------------------------------------------------
__global__ __launch_bounds__(256) void cast_split(
    const float* __restrict__ src, unsigned short* __restrict__ dst,
    int n4, int K3, int off_lo, int off_hi2)
{
    int i = blockIdx.x * 256 + threadIdx.x;
    if (i >= n4) return;
    const int r = i >> 7;              // Ksrc = 512 -> 128 float4 per row
    const int c = (i & 127) << 2;
    float4 x = *(const float4*)(src + (size_t)r * 512 + c);
    ushort4 hi = make_ushort4(f2bf(x.x), f2bf(x.y), f2bf(x.z), f2bf(x.w));
    ushort4 lo = make_ushort4(f2bf(x.x - bf2f(hi.x)), f2bf(x.y - bf2f(hi.y)),
                              f2bf(x.z - bf2f(hi.z)), f2bf(x.w - bf2f(hi.w)));
    unsigned short* dr = dst + (size_t)r * K3 + c;
    *(ushort4*)dr = hi;
    *(ushort4*)(dr + off_lo) = lo;
    if (off_hi2 >= 0) *(ushort4*)(dr + off_hi2) = hi;
}

// ---------------------------------------------------------------------------
// bf16 MFMA GEMM (m97 structure) with XCD-chunked + column-grouped swizzle.
// SPLIT: K'=1536 pairs A2=[A_hi|A_lo] (stride sA=1024, ko remap) with
// W2=[W_hi|W_lo|W_hi] (stride sW=1536): hi*hi + hi*lo + lo*hi.
// ---------------------------------------------------------------------------
__device__ __forceinline__ void gl_lds16(const unsigned short* g, unsigned short* l) {
    __builtin_amdgcn_global_load_lds((const __attribute__((address_space(1))) void*)g,
                                     (__attribute__((address_space(3))) void*)l, 16, 0, 0);
}
__device__ __forceinline__ int ko_map(bool split, int ko) {
    return (split && ko >= 512) ? ko - 512 : ko;
}

template <bool SPLIT>
__global__ __launch_bounds__(256) void gemm_bf16(
    const unsigned short* __restrict__ A,
    const unsigned short* __restrict__ W,
    const float* __restrict__ bias1, const float* __restrict__ bias2,
    float* __restrict__ C1, float* __restrict__ C2,
    int M, int N1, int N2, int K, int sA, int sW)
{
    // ---- block swizzle: XCD-chunk (nwg%8==0 by construction) then 7-col-group
    int bx, by;
    {
        const int nwg = gridDim.x * gridDim.y;
        int lin = blockIdx.y * gridDim.x + blockIdx.x;
        lin = (lin & 7) * (nwg >> 3) + (lin >> 3);          // contiguous per XCD
        const int G = (gridDim.x % 7 == 0) ? 7 : gridDim.x; // col-group width
        const int grpsz = gridDim.y * G;
        const int cg = lin / grpsz, rem = lin % grpsz;
        by = rem / G;
        bx = cg * G + rem % G;
    }
    const int Ntot = N1 + N2;
    const int bm = by * 128;
    const int bn = bx * 128;
    const int tid = threadIdx.x;
    const int lane = tid & 63;
    const int wid = tid >> 6;
    const int wr = wid >> 1;
    const int wc = wid & 1;

    __shared__ __align__(16) unsigned short As[2][4096];
    __shared__ __align__(16) unsigned short Bs[2][4096];

    const int arow = tid & 127;
    const int akg  = tid >> 7;
    const unsigned short* aSrc = A + (size_t)(bm + arow) * sA + akg * 8;
    int wrow = bn + arow; if (wrow >= Ntot) wrow = 0;
    const unsigned short* bSrc = W + (size_t)wrow * sW + akg * 8;
    const int gb0 = (wid * 64) * 8;
    const int gb1 = (256 + wid * 64) * 8;

    const int fA = (((lane >> 4) * 128) + wr * 64 + (lane & 15)) * 8;
    const int fB = (((lane >> 4) * 128) + wc * 64 + (lane & 15)) * 8;

    f32x4 acc[4][4] = {};
    const int NKT = K >> 5;

    gl_lds16(aSrc, &As[0][gb0]);
    gl_lds16(aSrc + 16, &As[0][gb1]);
    gl_lds16(bSrc, &Bs[0][gb0]);
    gl_lds16(bSrc + 16, &Bs[0][gb1]);
    __syncthreads();

    for (int kt = 0; kt < NKT; ++kt) {
        const int cur = kt & 1;
        if (kt + 1 < NKT) {
            const int ko  = (kt + 1) << 5;
            const int koA = ko_map(SPLIT, ko);
            gl_lds16(aSrc + koA, &As[cur ^ 1][gb0]);
            gl_lds16(aSrc + koA + 16, &As[cur ^ 1][gb1]);
            gl_lds16(bSrc + ko, &Bs[cur ^ 1][gb0]);
            gl_lds16(bSrc + ko + 16, &Bs[cur ^ 1][gb1]);
        }
        bf16x8 af[4], bfr[4];
#pragma unroll
        for (int m = 0; m < 4; ++m) af[m] = *(const bf16x8*)&As[cur][fA + m * 128];
#pragma unroll
        for (int n = 0; n < 4; ++n) bfr[n] = *(const bf16x8*)&Bs[cur][fB + n * 128];
#pragma unroll
        for (int m = 0; m < 4; ++m)
#pragma unroll
            for (int n = 0; n < 4; ++n)
                acc[m][n] = __builtin_amdgcn_mfma_f32_16x16x32_bf16(af[m], bfr[n], acc[m][n], 0, 0, 0);
        __syncthreads();
    }

    // epilogue: C/D layout col=lane&15, row=(lane>>4)*4+j  [m89]
#pragma unroll
    for (int n = 0; n < 4; ++n) {
        const int col = bn + wc * 64 + n * 16 + (lane & 15);
        if (col < Ntot) {
            const float bv = (col < N1) ? bias1[col] : bias2[col - N1];
#pragma unroll
            for (int m = 0; m < 4; ++m) {
                const int row0 = bm + wr * 64 + m * 16 + ((lane >> 4) << 2);
#pragma unroll
                for (int j = 0; j < 4; ++j) {
                    const float v = acc[m][n][j] + bv;
                    const int row = row0 + j;
                    if (col < N1)
                        C1[(size_t)row * N1 + col] = v;
                    else
                        C2[(size_t)row * N2 + (col - N1)] = v;
                }
            }
        }
    }
}

// ---------------------------------------------------------------------------
// DPP wave64 sum: row_shr 1/2/4/8, bcast15, bcast31 -> lane 63 -> readlane.
// ---------------------------------------------------------------------------
template <int CTRL, int RM>
__device__ __forceinline__ float dpp_radd(float x) {
    int t = __builtin_amdgcn_update_dpp(0, __builtin_bit_cast(int, x), CTRL, RM, 0xf, true);
    return x + __builtin_bit_cast(float, t);
}
__device__ __forceinline__ float wave_allsum(float x) {
    x = dpp_radd<0x111, 0xf>(x);
    x = dpp_radd<0x112, 0xf>(x);
    x = dpp_radd<0x114, 0xf>(x);
    x = dpp_radd<0x118, 0xf>(x);
    x = dpp_radd<0x142, 0xa>(x);
    x = dpp_radd<0x143, 0xc>(x);
    return __builtin_bit_cast(float, __builtin_amdgcn_readlane(__builtin_bit_cast(int, x), 63));
}

// np.float32 omegas: cos(pi*tt), cos(pi/3*tt)
__device__ __forceinline__ void osc2(float tt, float& oc03, float& oc12) {
    oc03 = cosf(3.14159265358979323846f * tt);
    oc12 = cosf(1.04719755119659774615f * tt);
}

// ===========================================================================
// Blocked scan.  Recurrence y[t] = a[t]*y[t-1] + x[t] is elementwise; chunk
// into NCH chunks of CH:  A) local scans (zero init) + decay products;
// B) serial combine over chunks (elementwise-parallel, in-place -> incoming);
// C) re-run each chunk from true incoming state, emit attn + final states.
// ===========================================================================

// Phase A: grid = NCH*BH blocks, 64 threads; lane d owns de = 4d..4d+3.
__global__ __launch_bounds__(64) void scanA(
    const float* __restrict__ kqv, const float* __restrict__ pbuf,
    const float* __restrict__ term, const float* __restrict__ tick,
    float* __restrict__ Dg, float* __restrict__ Db,
    float* __restrict__ Kloc, float* __restrict__ Vloc, float* __restrict__ Sloc)
{
    const int bh = blockIdx.x & (BH_ - 1);
    const int c  = blockIdx.x >> 8;
    const int b = bh >> 3, h = bh & 7;
    const int d = threadIdx.x;

    float K0[4] = {}, K1[4] = {}, K2[4] = {}, K3[4] = {}, S[4] = {};
    float V0 = 0.f, V1 = 0.f, V2 = 0.f, V3 = 0.f;
    float Dgv[4] = {1.f, 1.f, 1.f, 1.f};
    float Dbv = 1.f;
    const float tk = tick[b];

    for (int t = c * CH; t < (c + 1) * CH; ++t) {
        const float* kq = kqv + ((size_t)t * B_ + b) * NKQV + h * 320;
        const float c0 = kq[d], c2 = kq[128 + d], c3 = kq[192 + d], c4 = kq[256 + d];
        const float* pr = pbuf + ((size_t)t * B_ + b) * NP + h * 12;
        const float4 p1 = *(const float4*)pr;
        const float4 p3 = *(const float4*)(pr + 8);
        const float nt = 1.f - term[(size_t)t * B_ + b];

        float oc03, oc12; osc2(tk + (float)(t + 1), oc03, oc12);
        const float sgam = fsigm(c4);
        const float rk = fmaxf(c0, 0.f);
        const float sbet = fsigm(c3);
        const float vb = c2 * sbet;
        const float dbv = (1.f - sbet) * nt;
        const float p1a[4] = {p1.x, p1.y, p1.z, p1.w};
        const float p3a[4] = {p3.x, p3.y, p3.z, p3.w};
#pragma unroll
        for (int n = 0; n < 4; ++n) {
            const float g  = sgam * fsigm(p3a[n]);
            const float kg = rk * fmaxf(p1a[n], 0.f) * g;
            const float dg = (1.f - g) * nt;
            S[n]  = fmaf(dg, S[n],  kg);
            K0[n] = fmaf(dg, K0[n], kg * oc03);
            K1[n] = fmaf(dg, K1[n], kg * oc12);
            K2[n] = fmaf(dg, K2[n], kg * oc12);
            K3[n] = fmaf(dg, K3[n], kg * oc03);
            Dgv[n] *= dg;
        }
        V0 = fmaf(dbv, V0, vb * oc03);
        V1 = fmaf(dbv, V1, vb * oc12);
        V2 = fmaf(dbv, V2, vb * oc12);
        V3 = fmaf(dbv, V3, vb * oc03);
        Dbv *= dbv;
    }

    const size_t cb = (size_t)c * BH_ + bh;
    *(float4*)&Dg[cb * DE_ + 4 * d] = make_float4(Dgv[0], Dgv[1], Dgv[2], Dgv[3]);
    Db[cb * D_ + d] = Dbv;
    *(float4*)&Kloc[(cb * 4 + 0) * DE_ + 4 * d] = make_float4(K0[0], K0[1], K0[2], K0[3]);
    *(float4*)&Kloc[(cb * 4 + 1) * DE_ + 4 * d] = make_float4(K1[0], K1[1], K1[2], K1[3]);
    *(float4*)&Kloc[(cb * 4 + 2) * DE_ + 4 * d] = make_float4(K2[0], K2[1], K2[2], K2[3]);
    *(float4*)&Kloc[(cb * 4 + 3) * DE_ + 4 * d] = make_float4(K3[0], K3[1], K3[2], K3[3]);
    Vloc[(cb * 4 + 0) * D_ + d] = V0;
    Vloc[(cb * 4 + 1) * D_ + d] = V1;
    Vloc[(cb * 4 + 2) * D_ + d] = V2;
    Vloc[(cb * 4 + 3) * D_ + d] = V3;
    *(float4*)&Sloc[cb * DE_ + 4 * d] = make_float4(S[0], S[1], S[2], S[3]);
}

// Phase B: grid = BH blocks x 256 threads (de). Serial over chunks, in-place:
// loc[c] := incoming state of chunk c;  carry = Dg*carry + loc.
__global__ __launch_bounds__(256) void scanB(
    const float* __restrict__ k_prev, const float* __restrict__ v_prev,
    const float* __restrict__ s_prev,
    float* __restrict__ Dg, float* __restrict__ Db,
    float* __restrict__ Kloc, float* __restrict__ Vloc, float* __restrict__ Sloc)
{
    const int bh = blockIdx.x;
    const int b = bh >> 3, h = bh & 7;
    const int de = threadIdx.x;

    float Kin[4], Sin, Vin[4];
#pragma unroll
    for (int r = 0; r < 4; ++r)
        Kin[r] = k_prev[((size_t)(b * 4 + r) * 8 + h) * DE_ + de];
    Sin = s_prev[((size_t)b * 8 + h) * DE_ + de];
    if (de < D_) {
#pragma unroll
        for (int r = 0; r < 4; ++r)
            Vin[r] = v_prev[((size_t)(b * 4 + r) * 8 + h) * D_ + de];
    }

    for (int c = 0; c < NCH; ++c) {
        const size_t cb = (size_t)c * BH_ + bh;
        const float dg = Dg[cb * DE_ + de];
#pragma unroll
        for (int r = 0; r < 4; ++r) {
            const size_t ix = (cb * 4 + r) * DE_ + de;
            const float kl = Kloc[ix];
            Kloc[ix] = Kin[r];
            Kin[r] = fmaf(dg, Kin[r], kl);
        }
        {
            const size_t ix = cb * DE_ + de;
            const float sl = Sloc[ix];
            Sloc[ix] = Sin;
            Sin = fmaf(dg, Sin, sl);
        }
        if (de < D_) {
            const float db = Db[cb * D_ + de];
#pragma unroll
            for (int r = 0; r < 4; ++r) {
                const size_t ix = (cb * 4 + r) * D_ + de;
                const float vl = Vloc[ix];
                Vloc[ix] = Vin[r];
                Vin[r] = fmaf(db, Vin[r], vl);
            }
        }
    }
}

// Phase C: grid = NCH*BH blocks x 64; re-run chunk from incoming, emit attn.
__global__ __launch_bounds__(64) void scanC(
    const float* __restrict__ kqv, const float* __restrict__ pbuf,
    const float* __restrict__ term, const float* __restrict__ tick,
    const float* __restrict__ Kloc, const float* __restrict__ Vloc,
    const float* __restrict__ Sloc,
    unsigned short* __restrict__ attn,
    float* __restrict__ kf, float* __restrict__ vf, float* __restrict__ sf,
    float* __restrict__ tick_out)
{
    const int bh = blockIdx.x & (BH_ - 1);
    const int c  = blockIdx.x >> 8;
    const int b = bh >> 3, h = bh & 7;
    const int d = threadIdx.x;
    const size_t cb = (size_t)c * BH_ + bh;

    float K0[4], K1[4], K2[4], K3[4], S[4];
    float V0, V1, V2, V3;
    {
        float4 k4;
        k4 = *(const float4*)&Kloc[(cb * 4 + 0) * DE_ + 4 * d];
        K0[0] = k4.x; K0[1] = k4.y; K0[2] = k4.z; K0[3] = k4.w;
        k4 = *(const float4*)&Kloc[(cb * 4 + 1) * DE_ + 4 * d];
        K1[0] = k4.x; K1[1] = k4.y; K1[2] = k4.z; K1[3] = k4.w;
        k4 = *(const float4*)&Kloc[(cb * 4 + 2) * DE_ + 4 * d];
        K2[0] = k4.x; K2[1] = k4.y; K2[2] = k4.z; K2[3] = k4.w;
        k4 = *(const float4*)&Kloc[(cb * 4 + 3) * DE_ + 4 * d];
        K3[0] = k4.x; K3[1] = k4.y; K3[2] = k4.z; K3[3] = k4.w;
        k4 = *(const float4*)&Sloc[cb * DE_ + 4 * d];
        S[0] = k4.x; S[1] = k4.y; S[2] = k4.z; S[3] = k4.w;
        V0 = Vloc[(cb * 4 + 0) * D_ + d];
        V1 = Vloc[(cb * 4 + 1) * D_ + d];
        V2 = Vloc[(cb * 4 + 2) * D_ + d];
        V3 = Vloc[(cb * 4 + 3) * D_ + d];
    }
    const float tk = tick[b];

    for (int t = c * CH; t < (c + 1) * CH; ++t) {
        const float* kq = kqv + ((size_t)t * B_ + b) * NKQV + h * 320;
        const float c0 = kq[d], c1 = kq[64 + d], c2 = kq[128 + d],
                    c3 = kq[192 + d], c4 = kq[256 + d];
        const float* pr = pbuf + ((size_t)t * B_ + b) * NP + h * 12;
        const float4 p1 = *(const float4*)pr;
        const float4 p2 = *(const float4*)(pr + 4);
        const float4 p3 = *(const float4*)(pr + 8);
        const float nt = 1.f - term[(size_t)t * B_ + b];

        float oc03, oc12; osc2(tk + (float)(t + 1), oc03, oc12);
        const float sgam = fsigm(c4);
        const float rk = fmaxf(c0, 0.f);
        const float rq = fmaxf(c1, 0.f);
        const float sbet = fsigm(c3);
        const float vb = c2 * sbet;
        const float dbv = (1.f - sbet) * nt;
        const float p1a[4] = {p1.x, p1.y, p1.z, p1.w};
        const float p2a[4] = {p2.x, p2.y, p2.z, p2.w};
        const float p3a[4] = {p3.x, p3.y, p3.z, p3.w};

        float s0 = 0.f, s1 = 0.f, s2 = 0.f, s3 = 0.f, s4 = 0.f;
#pragma unroll
        for (int n = 0; n < 4; ++n) {
            const float g  = sgam * fsigm(p3a[n]);
            const float kg = rk * fmaxf(p1a[n], 0.f) * g;
            const float qe = rq * fmaxf(p2a[n], 0.f);
            const float dg = (1.f - g) * nt;
            S[n]  = fmaf(dg, S[n],  kg);
            K0[n] = fmaf(dg, K0[n], kg * oc03);
            K1[n] = fmaf(dg, K1[n], kg * oc12);
            K2[n] = fmaf(dg, K2[n], kg * oc12);
            K3[n] = fmaf(dg, K3[n], kg * oc03);
            s0 = fmaf(K0[n], qe, s0);
            s1 = fmaf(K1[n], qe, s1);
            s2 = fmaf(K2[n], qe, s2);
            s3 = fmaf(K3[n], qe, s3);
            s4 = fmaf(S[n],  qe, s4);
        }
        V0 = fmaf(dbv, V0, vb * oc03);
        V1 = fmaf(dbv, V1, vb * oc12);
        V2 = fmaf(dbv, V2, vb * oc12);
        V3 = fmaf(dbv, V3, vb * oc03);

        const float kdq0 = wave_allsum(s0);
        const float kdq1 = wave_allsum(s1);
        const float kdq2 = wave_allsum(s2);
        const float kdq3 = wave_allsum(s3);
        const float nrm  = wave_allsum(s4);

        const float kv = V0 * kdq0 + V1 * kdq1 + V2 * kdq2 + V3 * kdq3;
        attn[((size_t)t * B_ + b) * (H_ * D_) + h * D_ + d] =
            f2bf(__fdividef(kv, 2.f * (float)R_ * nrm + EPS_));
    }

    if (c == NCH - 1) {
        *(float4*)&kf[((size_t)(b * 4 + 0) * 8 + h) * DE_ + 4 * d] = make_float4(K0[0], K0[1], K0[2], K0[3]);
        *(float4*)&kf[((size_t)(b * 4 + 1) * 8 + h) * DE_ + 4 * d] = make_float4(K1[0], K1[1], K1[2], K1[3]);
        *(float4*)&kf[((size_t)(b * 4 + 2) * 8 + h) * DE_ + 4 * d] = make_float4(K2[0], K2[1], K2[2], K2[3]);
        *(float4*)&kf[((size_t)(b * 4 + 3) * 8 + h) * DE_ + 4 * d] = make_float4(K3[0], K3[1], K3[2], K3[3]);
        *(float4*)&sf[((size_t)b * 8 + h) * DE_ + 4 * d] = make_float4(S[0], S[1], S[2], S[3]);
        vf[((size_t)(b * 4 + 0) * 8 + h) * D_ + d] = V0;
        vf[((size_t)(b * 4 + 1) * 8 + h) * D_ + d] = V1;
        vf[((size_t)(b * 4 + 2) * 8 + h) * D_ + d] = V2;
        vf[((size_t)(b * 4 + 3) * 8 + h) * D_ + d] = V3;
        if (h == 0 && d == 0) tick_out[b] = tk + (float)T_;
    }
}

// ---------------------------------------------------------------------------
extern "C" void kernel_launch(void* const* d_in, const int* in_sizes, int n_in,
                              void* d_out, int out_size, void* d_ws, size_t ws_size,
                              hipStream_t stream)
{
    const float* inputs = (const float*)d_in[0];
    const float* term   = (const float*)d_in[1];
    const float* k_prev = (const float*)d_in[2];
    const float* v_prev = (const float*)d_in[3];
    const float* s_prev = (const float*)d_in[4];
    const float* tick   = (const float*)d_in[5];
    const float* W_kqv  = (const float*)d_in[6];
    const float* b_kqv  = (const float*)d_in[7];
    const float* W_p    = (const float*)d_in[8];
    const float* b_p    = (const float*)d_in[9];
    const float* W_o    = (const float*)d_in[10];
    const float* b_o    = (const float*)d_in[11];

    float* out = (float*)d_out;                       // (T,B,IN)
    float* kf  = out + (size_t)T_ * B_ * IN_;
    float* vf  = kf  + (size_t)B_ * R_ * H_ * DE_;
    float* sf  = vf  + (size_t)B_ * R_ * H_ * D_;
    float* tick_out = sf + (size_t)B_ * H_ * DE_;

    // workspace (~65 MB, same as R5)
    float* kqv_f  = (float*)d_ws;                                   // 4096x2560 f32  41.9MB
    float* p_f    = kqv_f + (size_t)M_ * NKQV;                      // 4096x96 f32     1.6MB
    unsigned short* attn_bf = (unsigned short*)(p_f + (size_t)M_ * NP);   // 4096x512 bf16 4.2MB
    unsigned short* Wo_bf   = attn_bf + (size_t)M_ * IN_;           // 512x512 bf16    0.5MB
    unsigned short* A2      = Wo_bf + (size_t)IN_ * (H_ * D_);      // 4096x1024 [hi|lo] 8.4MB
    unsigned short* W2      = A2 + (size_t)M_ * 1024;               // 2656x1536 [hi|lo|hi] 8.2MB

    // scan chunk arrays ALIAS A2+W2 (dead after the projection GEMM): 15.2MB
    float* Dg   = (float*)A2;                                       // [NCH][BH][DE]
    float* Db   = Dg   + (size_t)NCH * BH_ * DE_;                   // [NCH][BH][D]
    float* Kloc = Db   + (size_t)NCH * BH_ * D_;                    // [NCH][BH][4][DE]
    float* Vloc = Kloc + (size_t)NCH * BH_ * 4 * DE_;               // [NCH][BH][4][D]
    float* Sloc = Vloc + (size_t)NCH * BH_ * 4 * D_;                // [NCH][BH][DE]

    {   // splits + plain cast
        int n4 = M_ * 128;
        cast_split<<<(n4 + 255) / 256, 256, 0, stream>>>(inputs, A2, n4, 1024, 512, -1);
        n4 = NKQV * 128;
        cast_split<<<(n4 + 255) / 256, 256, 0, stream>>>(W_kqv, W2, n4, 1536, 512, 1024);
        n4 = NP * 128;
        cast_split<<<(n4 + 255) / 256, 256, 0, stream>>>(W_p, W2 + (size_t)NKQV * 1536, n4, 1536, 512, 1024);
        int n8 = (IN_ * (H_ * D_)) / 8;
        cast_f32_bf16<<<(n8 + 255) / 256, 256, 0, stream>>>(W_o, Wo_bf, n8);
    }

    {   // fused kqv+p projection, split-bf16: Ntot=2656, K'=1536
        dim3 grid((NKQV + NP + 127) / 128, M_ / 128);   // 21 x 32 = 672 (%8==0)
        gemm_bf16<true><<<grid, 256, 0, stream>>>(A2, W2, b_kqv, b_p,
                                                  kqv_f, p_f, M_, NKQV, NP,
                                                  1536, 1024, 1536);
    }

    // blocked scan: A (parallel local scans) -> B (combine) -> C (replay+attn)
    scanA<<<NCH * BH_, 64, 0, stream>>>(kqv_f, p_f, term, tick,
                                        Dg, Db, Kloc, Vloc, Sloc);
    scanB<<<BH_, 256, 0, stream>>>(k_prev, v_prev, s_prev,
                                   Dg, Db, Kloc, Vloc, Sloc);
    scanC<<<NCH * BH_, 64, 0, stream>>>(kqv_f, p_f, term, tick,
                                        Kloc, Vloc, Sloc, attn_bf,
                                        kf, vf, sf, tick_out);

    {   // output projection: plain bf16 MFMA, N=512, K=512
        dim3 grid(IN_ / 128, M_ / 128);                 // 4 x 32 = 128 (%8==0)
        gemm_bf16<false><<<grid, 256, 0, stream>>>(attn_bf, Wo_bf, b_o, b_o,
                                                   out, nullptr, M_, IN_, 0,
                                                   512, 512, 512);
    }
}

// Round 7
// 159.717 us; speedup vs baseline: 2.8309x; 1.0234x over previous
//
#include <hip/hip_runtime.h>
#include <math.h>
#include <stdint.h>

// Problem constants (match reference)
constexpr int T_ = 128, B_ = 32, IN_ = 512, H_ = 8, D_ = 64, ETA_ = 4, R_ = 4;
constexpr int DE_ = ETA_ * D_;          // 256
constexpr float EPS_ = 1e-5f;
constexpr int M_   = T_ * B_;           // 4096
constexpr int NCH  = 8;                 // scan chunks
constexpr int CH   = T_ / NCH;          // 16 steps per chunk
constexpr int BH_  = B_ * H_;           // 256

// Permuted fused-projection layout (kqv_s, width NW):
//   [0,512)     keys    col = h*64+d   (3-pass split, precision-critical)
//   [512,1024)  queries (split)
//   [1024,1536) gammas  (split)
//   [1536,1632) p       col = 1536 + h*12 + i*4 + n  (split)
//   [1632,1664) zero pad
//   [1664,2176) values  (1-pass bf16 — numerator-only sensitivity)
//   [2176,2688) beta    (1-pass)
constexpr int NW = 2688;
constexpr int SPLITCOL = 1664;          // cols < SPLITCOL use K=1536

typedef __attribute__((ext_vector_type(8))) short bf16x8;
typedef __attribute__((ext_vector_type(4))) float f32x4;

__device__ __forceinline__ float bf2f(unsigned short u) {
    return __builtin_bit_cast(float, ((unsigned)u) << 16);
}
__device__ __forceinline__ unsigned short f2bf(float f) {
    unsigned u = __builtin_bit_cast(unsigned, f);
    u = (u + 0x7fffu + ((u >> 16) & 1u)) >> 16;   // RNE
    return (unsigned short)u;
}
__device__ __forceinline__ float fsigm(float x) {
    return __fdividef(1.f, 1.f + __expf(-x));
}

// ---------------------------------------------------------------------------
// inputs -> A2 = [A_hi | A_lo] (stride 1024 shorts)
// ---------------------------------------------------------------------------
__global__ __launch_bounds__(256) void cast_splitA(
    const float* __restrict__ src, unsigned short* __restrict__ dst, int n4)
{
    int i = blockIdx.x * 256 + threadIdx.x;
    if (i >= n4) return;
    const int r = i >> 7;
    const int c = (i & 127) << 2;
    float4 x = *(const float4*)(src + (size_t)r * 512 + c);
    ushort4 hi = make_ushort4(f2bf(x.x), f2bf(x.y), f2bf(x.z), f2bf(x.w));
    ushort4 lo = make_ushort4(f2bf(x.x - bf2f(hi.x)), f2bf(x.y - bf2f(hi.y)),
                              f2bf(x.z - bf2f(hi.z)), f2bf(x.w - bf2f(hi.w)));
    unsigned short* dr = dst + (size_t)r * 1024 + c;
    *(ushort4*)dr = hi;
    *(ushort4*)(dr + 512) = lo;
}

// ---------------------------------------------------------------------------
// Build W2 (2688 rows x [hi|lo|hi], stride 1536) with the output-column
// permutation, plus bias_perm. Rows 1632..1663 are zero padding.
// ---------------------------------------------------------------------------
__global__ __launch_bounds__(256) void build_w2_bias(
    const float* __restrict__ Wkqv, const float* __restrict__ Wp,
    const float* __restrict__ bkqv, const float* __restrict__ bp,
    unsigned short* __restrict__ W2, float* __restrict__ bias_perm)
{
    int i = blockIdx.x * 256 + threadIdx.x;
    if (i >= NW * 128) return;
    const int rr = i >> 7;
    const int c = (i & 127) << 2;

    bool zero = false;
    const float* srow = nullptr;
    float bv = 0.f;
    if (rr < 512) {
        const int h = rr >> 6, dd = rr & 63, s = h * 320 + dd;
        srow = Wkqv + (size_t)s * 512; bv = bkqv[s];
    } else if (rr < 1024) {
        const int q = rr - 512, h = q >> 6, dd = q & 63, s = h * 320 + 64 + dd;
        srow = Wkqv + (size_t)s * 512; bv = bkqv[s];
    } else if (rr < 1536) {
        const int q = rr - 1024, h = q >> 6, dd = q & 63, s = h * 320 + 256 + dd;
        srow = Wkqv + (size_t)s * 512; bv = bkqv[s];
    } else if (rr < 1632) {
        const int q = rr - 1536;
        srow = Wp + (size_t)q * 512; bv = bp[q];
    } else if (rr < 1664) {
        zero = true;
    } else if (rr < 2176) {
        const int q = rr - 1664, h = q >> 6, dd = q & 63, s = h * 320 + 128 + dd;
        srow = Wkqv + (size_t)s * 512; bv = bkqv[s];
    } else {
        const int q = rr - 2176, h = q >> 6, dd = q & 63, s = h * 320 + 192 + dd;
        srow = Wkqv + (size_t)s * 512; bv = bkqv[s];
    }

    float4 x = zero ? make_float4(0.f, 0.f, 0.f, 0.f) : *(const float4*)(srow + c);
    ushort4 hi = make_ushort4(f2bf(x.x), f2bf(x.y), f2bf(x.z), f2bf(x.w));
    ushort4 lo = make_ushort4(f2bf(x.x - bf2f(hi.x)), f2bf(x.y - bf2f(hi.y)),
                              f2bf(x.z - bf2f(hi.z)), f2bf(x.w - bf2f(hi.w)));
    unsigned short* dr = W2 + (size_t)rr * 1536 + c;
    *(ushort4*)dr = hi;
    *(ushort4*)(dr + 512) = lo;
    *(ushort4*)(dr + 1024) = hi;
    if (c == 0) bias_perm[rr] = zero ? 0.f : bv;
}

// ---------------------------------------------------------------------------
// fp32 -> bf16 cast (W_o)
// ---------------------------------------------------------------------------
__global__ __launch_bounds__(256) void cast_f32_bf16(
    const float* __restrict__ src, unsigned short* __restrict__ dst, int n8)
{
    int i = blockIdx.x * 256 + threadIdx.x;
    if (i >= n8) return;
    const float4* s = (const float4*)src;
    float4 a = s[2 * i], b = s[2 * i + 1];
    *(ushort4*)(dst + 8 * i)     = make_ushort4(f2bf(a.x), f2bf(a.y), f2bf(a.z), f2bf(a.w));
    *(ushort4*)(dst + 8 * i + 4) = make_ushort4(f2bf(b.x), f2bf(b.y), f2bf(b.z), f2bf(b.w));
}

// ---------------------------------------------------------------------------
// bf16 MFMA GEMM (m97 structure) + XCD/column-group swizzle.
// Per-block K: bn < splitcol ? kBig : kSmall. A k-offset >= 512 remaps to
// A_lo (split pairing hi*hi, hi*lo, lo*hi). N, M multiples of 128 (no guards).
// ---------------------------------------------------------------------------
__device__ __forceinline__ void gl_lds16(const unsigned short* g, unsigned short* l) {
    __builtin_amdgcn_global_load_lds((const __attribute__((address_space(1))) void*)g,
                                     (__attribute__((address_space(3))) void*)l, 16, 0, 0);
}

__global__ __launch_bounds__(256) void gemm_bf16(
    const unsigned short* __restrict__ A,
    const unsigned short* __restrict__ W,
    const float* __restrict__ bias,
    float* __restrict__ C,
    int N, int sA, int sW, int kBig, int kSmall, int splitcol)
{
    // block swizzle: XCD-chunk (nwg%8==0) then col-group of 7 (if divisible)
    int bx, by;
    {
        const int nwg = gridDim.x * gridDim.y;
        int lin = blockIdx.y * gridDim.x + blockIdx.x;
        lin = (lin & 7) * (nwg >> 3) + (lin >> 3);
        const int G = (gridDim.x % 7 == 0) ? 7 : gridDim.x;
        const int grpsz = gridDim.y * G;
        const int cg = lin / grpsz, rem = lin % grpsz;
        by = rem / G;
        bx = cg * G + rem % G;
    }
    const int bm = by * 128;
    const int bn = bx * 128;
    const int tid = threadIdx.x;
    const int lane = tid & 63;
    const int wid = tid >> 6;
    const int wr = wid >> 1;
    const int wc = wid & 1;

    __shared__ __align__(16) unsigned short As[2][4096];
    __shared__ __align__(16) unsigned short Bs[2][4096];

    const int arow = tid & 127;
    const int akg  = tid >> 7;
    const unsigned short* aSrc = A + (size_t)(bm + arow) * sA + akg * 8;
    const unsigned short* bSrc = W + (size_t)(bn + arow) * sW + akg * 8;
    const int gb0 = (wid * 64) * 8;
    const int gb1 = (256 + wid * 64) * 8;

    const int fA = (((lane >> 4) * 128) + wr * 64 + (lane & 15)) * 8;
    const int fB = (((lane >> 4) * 128) + wc * 64 + (lane & 15)) * 8;

    f32x4 acc[4][4] = {};
    const int K = (bn < splitcol) ? kBig : kSmall;
    const int NKT = K >> 5;

    gl_lds16(aSrc, &As[0][gb0]);
    gl_lds16(aSrc + 16, &As[0][gb1]);
    gl_lds16(bSrc, &Bs[0][gb0]);
    gl_lds16(bSrc + 16, &Bs[0][gb1]);
    __syncthreads();

    for (int kt = 0; kt < NKT; ++kt) {
        const int cur = kt & 1;
        if (kt + 1 < NKT) {
            const int ko  = (kt + 1) << 5;
            const int koA = (ko >= 512) ? ko - 512 : ko;   // A: [hi|lo] pairing
            gl_lds16(aSrc + koA, &As[cur ^ 1][gb0]);
            gl_lds16(aSrc + koA + 16, &As[cur ^ 1][gb1]);
            gl_lds16(bSrc + ko, &Bs[cur ^ 1][gb0]);
            gl_lds16(bSrc + ko + 16, &Bs[cur ^ 1][gb1]);
        }
        bf16x8 af[4], bfr[4];
#pragma unroll
        for (int m = 0; m < 4; ++m) af[m] = *(const bf16x8*)&As[cur][fA + m * 128];
#pragma unroll
        for (int n = 0; n < 4; ++n) bfr[n] = *(const bf16x8*)&Bs[cur][fB + n * 128];
#pragma unroll
        for (int m = 0; m < 4; ++m)
#pragma unroll
            for (int n = 0; n < 4; ++n)
                acc[m][n] = __builtin_amdgcn_mfma_f32_16x16x32_bf16(af[m], bfr[n], acc[m][n], 0, 0, 0);
        __syncthreads();
    }

    // epilogue: C/D layout col=lane&15, row=(lane>>4)*4+j  [m89]
#pragma unroll
    for (int n = 0; n < 4; ++n) {
        const int col = bn + wc * 64 + n * 16 + (lane & 15);
        const float bv = bias[col];
#pragma unroll
        for (int m = 0; m < 4; ++m) {
            const int row0 = bm + wr * 64 + m * 16 + ((lane >> 4) << 2);
#pragma unroll
            for (int j = 0; j < 4; ++j)
                C[(size_t)(row0 + j) * N + col] = acc[m][n][j] + bv;
        }
    }
}

// ---------------------------------------------------------------------------
// DPP wave64 sum: row_shr 1/2/4/8, bcast15, bcast31 -> lane 63 -> readlane.
// ---------------------------------------------------------------------------
template <int CTRL, int RM>
__device__ __forceinline__ float dpp_radd(float x) {
    int t = __builtin_amdgcn_update_dpp(0, __builtin_bit_cast(int, x), CTRL, RM, 0xf, true);
    return x + __builtin_bit_cast(float, t);
}
__device__ __forceinline__ float wave_allsum(float x) {
    x = dpp_radd<0x111, 0xf>(x);
    x = dpp_radd<0x112, 0xf>(x);
    x = dpp_radd<0x114, 0xf>(x);
    x = dpp_radd<0x118, 0xf>(x);
    x = dpp_radd<0x142, 0xa>(x);
    x = dpp_radd<0x143, 0xc>(x);
    return __builtin_bit_cast(float, __builtin_amdgcn_readlane(__builtin_bit_cast(int, x), 63));
}

// np.float32 omegas: cos(pi*tt), cos(pi/3*tt)
__device__ __forceinline__ void osc2(float tt, float& oc03, float& oc12) {
    oc03 = cosf(3.14159265358979323846f * tt);
    oc12 = cosf(1.04719755119659774615f * tt);
}

// ===========================================================================
// Blocked scan over permuted kqv_s (width NW).
// ===========================================================================

// Phase A: grid = NCH*BH blocks, 64 threads; lane d owns de = 4d..4d+3.
__global__ __launch_bounds__(64) void scanA(
    const float* __restrict__ kqv, const float* __restrict__ term,
    const float* __restrict__ tick,
    float* __restrict__ Dg, float* __restrict__ Db,
    float* __restrict__ Kloc, float* __restrict__ Vloc, float* __restrict__ Sloc)
{
    const int bh = blockIdx.x & (BH_ - 1);
    const int c  = blockIdx.x >> 8;
    const int b = bh >> 3, h = bh & 7;
    const int d = threadIdx.x;

    float K0[4] = {}, K1[4] = {}, K2[4] = {}, K3[4] = {}, S[4] = {};
    float V0 = 0.f, V1 = 0.f, V2 = 0.f, V3 = 0.f;
    float Dgv[4] = {1.f, 1.f, 1.f, 1.f};
    float Dbv = 1.f;
    const float tk = tick[b];

    for (int t = c * CH; t < (c + 1) * CH; ++t) {
        const float* row = kqv + ((size_t)t * B_ + b) * NW;
        const float c0 = row[h * 64 + d];                 // keys
        const float c2 = row[1664 + h * 64 + d];          // values
        const float c3 = row[2176 + h * 64 + d];          // beta
        const float c4 = row[1024 + h * 64 + d];          // gammas
        const float* pr = row + 1536 + h * 12;
        const float4 p1 = *(const float4*)pr;
        const float4 p3 = *(const float4*)(pr + 8);
        const float nt = 1.f - term[(size_t)t * B_ + b];

        float oc03, oc12; osc2(tk + (float)(t + 1), oc03, oc12);
        const float sgam = fsigm(c4);
        const float rk = fmaxf(c0, 0.f);
        const float sbet = fsigm(c3);
        const float vb = c2 * sbet;
        const float dbv = (1.f - sbet) * nt;
        const float p1a[4] = {p1.x, p1.y, p1.z, p1.w};
        const float p3a[4] = {p3.x, p3.y, p3.z, p3.w};
#pragma unroll
        for (int n = 0; n < 4; ++n) {
            const float g  = sgam * fsigm(p3a[n]);
            const float kg = rk * fmaxf(p1a[n], 0.f) * g;
            const float dg = (1.f - g) * nt;
            S[n]  = fmaf(dg, S[n],  kg);
            K0[n] = fmaf(dg, K0[n], kg * oc03);
            K1[n] = fmaf(dg, K1[n], kg * oc12);
            K2[n] = fmaf(dg, K2[n], kg * oc12);
            K3[n] = fmaf(dg, K3[n], kg * oc03);
            Dgv[n] *= dg;
        }
        V0 = fmaf(dbv, V0, vb * oc03);
        V1 = fmaf(dbv, V1, vb * oc12);
        V2 = fmaf(dbv, V2, vb * oc12);
        V3 = fmaf(dbv, V3, vb * oc03);
        Dbv *= dbv;
    }

    const size_t cb = (size_t)c * BH_ + bh;
    *(float4*)&Dg[cb * DE_ + 4 * d] = make_float4(Dgv[0], Dgv[1], Dgv[2], Dgv[3]);
    Db[cb * D_ + d] = Dbv;
    *(float4*)&Kloc[(cb * 4 + 0) * DE_ + 4 * d] = make_float4(K0[0], K0[1], K0[2], K0[3]);
    *(float4*)&Kloc[(cb * 4 + 1) * DE_ + 4 * d] = make_float4(K1[0], K1[1], K1[2], K1[3]);
    *(float4*)&Kloc[(cb * 4 + 2) * DE_ + 4 * d] = make_float4(K2[0], K2[1], K2[2], K2[3]);
    *(float4*)&Kloc[(cb * 4 + 3) * DE_ + 4 * d] = make_float4(K3[0], K3[1], K3[2], K3[3]);
    Vloc[(cb * 4 + 0) * D_ + d] = V0;
    Vloc[(cb * 4 + 1) * D_ + d] = V1;
    Vloc[(cb * 4 + 2) * D_ + d] = V2;
    Vloc[(cb * 4 + 3) * D_ + d] = V3;
    *(float4*)&Sloc[cb * DE_ + 4 * d] = make_float4(S[0], S[1], S[2], S[3]);
}

// Phase B: grid = BH blocks x 256 threads (de). Serial over chunks, in-place:
// loc[c] := incoming state of chunk c;  carry = D*carry + loc.
__global__ __launch_bounds__(256) void scanB(
    const float* __restrict__ k_prev, const float* __restrict__ v_prev,
    const float* __restrict__ s_prev,
    float* __restrict__ Dg, float* __restrict__ Db,
    float* __restrict__ Kloc, float* __restrict__ Vloc, float* __restrict__ Sloc)
{
    const int bh = blockIdx.x;
    const int b = bh >> 3, h = bh & 7;
    const int de = threadIdx.x;

    float Kin[4], Sin, Vin[4];
#pragma unroll
    for (int r = 0; r < 4; ++r)
        Kin[r] = k_prev[((size_t)(b * 4 + r) * 8 + h) * DE_ + de];
    Sin = s_prev[((size_t)b * 8 + h) * DE_ + de];
    if (de < D_) {
#pragma unroll
        for (int r = 0; r < 4; ++r)
            Vin[r] = v_prev[((size_t)(b * 4 + r) * 8 + h) * D_ + de];
    }

    for (int c = 0; c < NCH; ++c) {
        const size_t cb = (size_t)c * BH_ + bh;
        const float dg = Dg[cb * DE_ + de];
#pragma unroll
        for (int r = 0; r < 4; ++r) {
            const size_t ix = (cb * 4 + r) * DE_ + de;
            const float kl = Kloc[ix];
            Kloc[ix] = Kin[r];
            Kin[r] = fmaf(dg, Kin[r], kl);
        }
        {
            const size_t ix = cb * DE_ + de;
            const float sl = Sloc[ix];
            Sloc[ix] = Sin;
            Sin = fmaf(dg, Sin, sl);
        }
        if (de < D_) {
            const float db = Db[cb * D_ + de];
#pragma unroll
            for (int r = 0; r < 4; ++r) {
                const size_t ix = (cb * 4 + r) * D_ + de;
                const float vl = Vloc[ix];
                Vloc[ix] = Vin[r];
                Vin[r] = fmaf(db, Vin[r], vl);
            }
        }
    }
}

// Phase C: grid = NCH*BH blocks x 64; re-run chunk from incoming, emit attn.
__global__ __launch_bounds__(64) void scanC(
    const float* __restrict__ kqv, const float* __restrict__ term,
    const float* __restrict__ tick,
    const float* __restrict__ Kloc, const float* __restrict__ Vloc,
    const float* __restrict__ Sloc,
    unsigned short* __restrict__ attn,
    float* __restrict__ kf, float* __restrict__ vf, float* __restrict__ sf,
    float* __restrict__ tick_out)
{
    const int bh = blockIdx.x & (BH_ - 1);
    const int c  = blockIdx.x >> 8;
    const int b = bh >> 3, h = bh & 7;
    const int d = threadIdx.x;
    const size_t cb = (size_t)c * BH_ + bh;

    float K0[4], K1[4], K2[4], K3[4], S[4];
    float V0, V1, V2, V3;
    {
        float4 k4;
        k4 = *(const float4*)&Kloc[(cb * 4 + 0) * DE_ + 4 * d];
        K0[0] = k4.x; K0[1] = k4.y; K0[2] = k4.z; K0[3] = k4.w;
        k4 = *(const float4*)&Kloc[(cb * 4 + 1) * DE_ + 4 * d];
        K1[0] = k4.x; K1[1] = k4.y; K1[2] = k4.z; K1[3] = k4.w;
        k4 = *(const float4*)&Kloc[(cb * 4 + 2) * DE_ + 4 * d];
        K2[0] = k4.x; K2[1] = k4.y; K2[2] = k4.z; K2[3] = k4.w;
        k4 = *(const float4*)&Kloc[(cb * 4 + 3) * DE_ + 4 * d];
        K3[0] = k4.x; K3[1] = k4.y; K3[2] = k4.z; K3[3] = k4.w;
        k4 = *(const float4*)&Sloc[cb * DE_ + 4 * d];
        S[0] = k4.x; S[1] = k4.y; S[2] = k4.z; S[3] = k4.w;
        V0 = Vloc[(cb * 4 + 0) * D_ + d];
        V1 = Vloc[(cb * 4 + 1) * D_ + d];
        V2 = Vloc[(cb * 4 + 2) * D_ + d];
        V3 = Vloc[(cb * 4 + 3) * D_ + d];
    }
    const float tk = tick[b];

    for (int t = c * CH; t < (c + 1) * CH; ++t) {
        const float* row = kqv + ((size_t)t * B_ + b) * NW;
        const float c0 = row[h * 64 + d];                 // keys
        const float c1 = row[512 + h * 64 + d];           // queries
        const float c2 = row[1664 + h * 64 + d];          // values
        const float c3 = row[2176 + h * 64 + d];          // beta
        const float c4 = row[1024 + h * 64 + d];          // gammas
        const float* pr = row + 1536 + h * 12;
        const float4 p1 = *(const float4*)pr;
        const float4 p2 = *(const float4*)(pr + 4);
        const float4 p3 = *(const float4*)(pr + 8);
        const float nt = 1.f - term[(size_t)t * B_ + b];

        float oc03, oc12; osc2(tk + (float)(t + 1), oc03, oc12);
        const float sgam = fsigm(c4);
        const float rk = fmaxf(c0, 0.f);
        const float rq = fmaxf(c1, 0.f);
        const float sbet = fsigm(c3);
        const float vb = c2 * sbet;
        const float dbv = (1.f - sbet) * nt;
        const float p1a[4] = {p1.x, p1.y, p1.z, p1.w};
        const float p2a[4] = {p2.x, p2.y, p2.z, p2.w};
        const float p3a[4] = {p3.x, p3.y, p3.z, p3.w};

        float s0 = 0.f, s1 = 0.f, s2 = 0.f, s3 = 0.f, s4 = 0.f;
#pragma unroll
        for (int n = 0; n < 4; ++n) {
            const float g  = sgam * fsigm(p3a[n]);
            const float kg = rk * fmaxf(p1a[n], 0.f) * g;
            const float qe = rq * fmaxf(p2a[n], 0.f);
            const float dg = (1.f - g) * nt;
            S[n]  = fmaf(dg, S[n],  kg);
            K0[n] = fmaf(dg, K0[n], kg * oc03);
            K1[n] = fmaf(dg, K1[n], kg * oc12);
            K2[n] = fmaf(dg, K2[n], kg * oc12);
            K3[n] = fmaf(dg, K3[n], kg * oc03);
            s0 = fmaf(K0[n], qe, s0);
            s1 = fmaf(K1[n], qe, s1);
            s2 = fmaf(K2[n], qe, s2);
            s3 = fmaf(K3[n], qe, s3);
            s4 = fmaf(S[n],  qe, s4);
        }
        V0 = fmaf(dbv, V0, vb * oc03);
        V1 = fmaf(dbv, V1, vb * oc12);
        V2 = fmaf(dbv, V2, vb * oc12);
        V3 = fmaf(dbv, V3, vb * oc03);

        const float kdq0 = wave_allsum(s0);
        const float kdq1 = wave_allsum(s1);
        const float kdq2 = wave_allsum(s2);
        const float kdq3 = wave_allsum(s3);
        const float nrm  = wave_allsum(s4);

        const float kv = V0 * kdq0 + V1 * kdq1 + V2 * kdq2 + V3 * kdq3;
        attn[((size_t)t * B_ + b) * (H_ * D_) + h * D_ + d] =
            f2bf(__fdividef(kv, 2.f * (float)R_ * nrm + EPS_));
    }

    if (c == NCH - 1) {
        *(float4*)&kf[((size_t)(b * 4 + 0) * 8 + h) * DE_ + 4 * d] = make_float4(K0[0], K0[1], K0[2], K0[3]);
        *(float4*)&kf[((size_t)(b * 4 + 1) * 8 + h) * DE_ + 4 * d] = make_float4(K1[0], K1[1], K1[2], K1[3]);
        *(float4*)&kf[((size_t)(b * 4 + 2) * 8 + h) * DE_ + 4 * d] = make_float4(K2[0], K2[1], K2[2], K2[3]);
        *(float4*)&kf[((size_t)(b * 4 + 3) * 8 + h) * DE_ + 4 * d] = make_float4(K3[0], K3[1], K3[2], K3[3]);
        *(float4*)&sf[((size_t)b * 8 + h) * DE_ + 4 * d] = make_float4(S[0], S[1], S[2], S[3]);
        vf[((size_t)(b * 4 + 0) * 8 + h) * D_ + d] = V0;
        vf[((size_t)(b * 4 + 1) * 8 + h) * D_ + d] = V1;
        vf[((size_t)(b * 4 + 2) * 8 + h) * D_ + d] = V2;
        vf[((size_t)(b * 4 + 3) * 8 + h) * D_ + d] = V3;
        if (h == 0 && d == 0) tick_out[b] = tk + (float)T_;
    }
}

// ---------------------------------------------------------------------------
extern "C" void kernel_launch(void* const* d_in, const int* in_sizes, int n_in,
                              void* d_out, int out_size, void* d_ws, size_t ws_size,
                              hipStream_t stream)
{
    const float* inputs = (const float*)d_in[0];
    const float* term   = (const float*)d_in[1];
    const float* k_prev = (const float*)d_in[2];
    const float* v_prev = (const float*)d_in[3];
    const float* s_prev = (const float*)d_in[4];
    const float* tick   = (const float*)d_in[5];
    const float* W_kqv  = (const float*)d_in[6];
    const float* b_kqv  = (const float*)d_in[7];
    const float* W_p    = (const float*)d_in[8];
    const float* b_p    = (const float*)d_in[9];
    const float* W_o    = (const float*)d_in[10];
    const float* b_o    = (const float*)d_in[11];

    float* out = (float*)d_out;                       // (T,B,IN)
    float* kf  = out + (size_t)T_ * B_ * IN_;
    float* vf  = kf  + (size_t)B_ * R_ * H_ * DE_;
    float* sf  = vf  + (size_t)B_ * R_ * H_ * D_;
    float* tick_out = sf + (size_t)B_ * H_ * DE_;

    // workspace (~65.4 MB)
    float* kqv_s = (float*)d_ws;                                    // 4096 x 2688 f32  44.0MB
    unsigned short* attn_bf = (unsigned short*)(kqv_s + (size_t)M_ * NW); // 4096x512 bf16 4.2MB
    unsigned short* Wo_bf   = attn_bf + (size_t)M_ * IN_;           // 512x512 bf16     0.5MB
    unsigned short* A2      = Wo_bf + (size_t)IN_ * (H_ * D_);      // 4096x1024 [hi|lo] 8.4MB
    unsigned short* W2      = A2 + (size_t)M_ * 1024;               // 2688x1536 [hi|lo|hi] 8.3MB
    float* bias_perm        = (float*)(W2 + (size_t)NW * 1536);     // 2688 f32

    // scan chunk arrays ALIAS A2+W2 (dead after projection GEMM): 15.2MB < 16.7MB
    float* Dg   = (float*)A2;                                       // [NCH][BH][DE]
    float* Db   = Dg   + (size_t)NCH * BH_ * DE_;                   // [NCH][BH][D]
    float* Kloc = Db   + (size_t)NCH * BH_ * D_;                    // [NCH][BH][4][DE]
    float* Vloc = Kloc + (size_t)NCH * BH_ * 4 * DE_;               // [NCH][BH][4][D]
    float* Sloc = Vloc + (size_t)NCH * BH_ * 4 * D_;                // [NCH][BH][DE]

    {   // prep: A split, W2+bias build (permuted), W_o cast
        int n4 = M_ * 128;
        cast_splitA<<<(n4 + 255) / 256, 256, 0, stream>>>(inputs, A2, n4);
        n4 = NW * 128;
        build_w2_bias<<<(n4 + 255) / 256, 256, 0, stream>>>(W_kqv, W_p, b_kqv, b_p,
                                                            W2, bias_perm);
        int n8 = (IN_ * (H_ * D_)) / 8;
        cast_f32_bf16<<<(n8 + 255) / 256, 256, 0, stream>>>(W_o, Wo_bf, n8);
    }

    {   // fused projection, selective split: 13 tiles K=1536, 8 tiles K=512
        dim3 grid(NW / 128, M_ / 128);                  // 21 x 32 = 672 (%8==0, %7 ok)
        gemm_bf16<<<grid, 256, 0, stream>>>(A2, W2, bias_perm, kqv_s,
                                            NW, 1024, 1536, 1536, 512, SPLITCOL);
    }

    // blocked scan: A (parallel local scans) -> B (combine) -> C (replay+attn)
    scanA<<<NCH * BH_, 64, 0, stream>>>(kqv_s, term, tick, Dg, Db, Kloc, Vloc, Sloc);
    scanB<<<BH_, 256, 0, stream>>>(k_prev, v_prev, s_prev, Dg, Db, Kloc, Vloc, Sloc);
    scanC<<<NCH * BH_, 64, 0, stream>>>(kqv_s, term, tick, Kloc, Vloc, Sloc,
                                        attn_bf, kf, vf, sf, tick_out);

    {   // output projection: plain bf16 MFMA, N=512, K=512
        dim3 grid(IN_ / 128, M_ / 128);                 // 4 x 32 = 128 (%8==0)
        gemm_bf16<<<grid, 256, 0, stream>>>(attn_bf, Wo_bf, b_o, out,
                                            IN_, 512, 512, 512, 512, 0);
    }
}